// Round 15
// baseline (937.144 us; speedup 1.0000x reference)
//
#include <hip/hip_runtime.h>
#include <math.h>

#define EMBED 768
#define HEADS 12
#define DH 64
#define DEPTH 6
#define MLP_DIM 3072
#define N_REAL 2049
#define SP 2112            // fp32 buffer row padding (33*64)
#define SPAD 2176          // bf16 activation row padding (17*128)
#define NEGV (-1e9f)

typedef __attribute__((ext_vector_type(8))) short short8;
typedef __attribute__((ext_vector_type(4))) float f32x4;

__device__ __forceinline__ unsigned short f2bf(float f) {
    union { float f; unsigned u; } x; x.f = f;
    unsigned r = x.u + 0x7FFF + ((x.u >> 16) & 1);
    return (unsigned short)(r >> 16);
}
__device__ __forceinline__ float bf2f(unsigned short s) {
    union { unsigned u; float f; } x; x.u = (unsigned)s << 16;
    return x.f;
}

// packed fragment-blob index: blobs of 16 "major" (row for A / col for B) x 32 k.
// entry (l*8+e) of blob = element (major = l&15, k = (l>>4)*8 + e).
__device__ __forceinline__ size_t pidx(int mj, int k, int nkt) {
    return (((size_t)(mj >> 4) * nkt + (k >> 5)) << 9) + (size_t)((((k >> 3) & 3) * 16 + (mj & 15)) * 8 + (k & 7));
}

// ---------------- im2col: x -> packed patch blobs (A-layout, nkt=32) ----------------
__global__ void im2col_kernel(const float* __restrict__ x, unsigned short* __restrict__ p) {
    const int pi = blockIdx.x;            // 0..2047
    const int d = pi >> 8, rr = (pi >> 4) & 15, cc = pi & 15;
    const int t = threadIdx.x;            // 256
    #pragma unroll
    for (int u = 0; u < 4; ++u) {
        int i = u * 256 + t;              // 0..1023
        int kd = i >> 8, kr = (i >> 4) & 15, kc = i & 15;
        float v = x[(size_t)(d * 4 + kd) * 65536 + (rr * 16 + kr) * 256 + (cc * 16 + kc)];
        p[pidx(pi, i, 32)] = f2bf(v);
    }
}

// ---------------- weight pack: fp32 [K][N] -> fragment blobs (B-layout) ----------------
__device__ __forceinline__ void pack_KN_body(const float* __restrict__ src,
                                             unsigned short* __restrict__ dst,
                                             int N, int K, int bn, int bk) {
    __shared__ float lf[128][33];         // [n][k]
    const int t = threadIdx.x;
    {
        const int kk = t >> 3, ch = t & 7;
        const float4* s = (const float4*)(src + (size_t)(bk * 32 + kk) * N + bn * 128 + ch * 16);
        float4 v0 = s[0], v1 = s[1], v2 = s[2], v3 = s[3];
        float tmp[16];
        ((float4*)tmp)[0] = v0; ((float4*)tmp)[1] = v1; ((float4*)tmp)[2] = v2; ((float4*)tmp)[3] = v3;
        #pragma unroll
        for (int u = 0; u < 16; ++u) lf[ch * 16 + u][kk] = tmp[u];
    }
    __syncthreads();
    const int nkt = K >> 5;
    const int cg = t >> 5;                // blob 0..7
    const int l0 = (t & 31) * 2;
    unsigned short* o = dst + (((size_t)(bn * 8 + cg) * nkt + bk) << 9);
    #pragma unroll
    for (int q = 0; q < 2; ++q) {
        const int l = l0 + q;
        const int col = cg * 16 + (l & 15), kb = (l >> 4) * 8;
        unsigned short ov[8];
        #pragma unroll
        for (int e = 0; e < 8; ++e) ov[e] = f2bf(lf[col][kb + e]);
        *(short8*)(o + l * 8) = *(short8*)ov;
    }
}

// one launch packs a whole layer: 4x[768][768] (576 blocks) + w1 (576) + w2 (576)
__global__ void pack_all_kernel(const float* __restrict__ wq, const float* __restrict__ wk,
                                const float* __restrict__ wv, const float* __restrict__ wo,
                                const float* __restrict__ w1s, const float* __restrict__ w2s,
                                unsigned short* __restrict__ qkv_pk, unsigned short* __restrict__ o_pk,
                                unsigned short* __restrict__ w1_pk, unsigned short* __restrict__ w2_pk) {
    const int fid = blockIdx.x;
    if (fid < 576) {
        const int m = fid / 144, r = fid % 144;
        const float* src = (m == 0) ? wq : (m == 1) ? wk : (m == 2) ? wv : wo;
        unsigned short* dst = (m < 3) ? qkv_pk + (size_t)m * EMBED * EMBED : o_pk;
        pack_KN_body(src, dst, EMBED, EMBED, r % 6, r / 6);
    } else if (fid < 1152) {
        const int r = fid - 576;
        pack_KN_body(w1s, w1_pk, MLP_DIM, EMBED, r % 24, r / 24);
    } else {
        const int r = fid - 1152;
        pack_KN_body(w2s, w2_pk, EMBED, MLP_DIM, r % 6, r / 6);
    }
}

// pack from fp32 [N][K] (conv_w: [768][1024])
__global__ void pack_NK_kernel(const float* __restrict__ src, unsigned short* __restrict__ dst,
                               int N, int K) {
    __shared__ float lf[128][33];
    const int bn = blockIdx.x, bk = blockIdx.y;
    const int t = threadIdx.x;
    {
        const int row = t >> 1, hf = t & 1;
        const float4* s = (const float4*)(src + (size_t)(bn * 128 + row) * K + bk * 32 + hf * 16);
        float4 v0 = s[0], v1 = s[1], v2 = s[2], v3 = s[3];
        float tmp[16];
        ((float4*)tmp)[0] = v0; ((float4*)tmp)[1] = v1; ((float4*)tmp)[2] = v2; ((float4*)tmp)[3] = v3;
        #pragma unroll
        for (int u = 0; u < 16; ++u) lf[row][hf * 16 + u] = tmp[u];
    }
    __syncthreads();
    const int nkt = K >> 5;
    const int cg = t >> 5;
    const int l0 = (t & 31) * 2;
    unsigned short* o = dst + (((size_t)(bn * 8 + cg) * nkt + bk) << 9);
    #pragma unroll
    for (int q = 0; q < 2; ++q) {
        const int l = l0 + q;
        const int col = cg * 16 + (l & 15), kb = (l >> 4) * 8;
        unsigned short ov[8];
        #pragma unroll
        for (int e = 0; e < 8; ++e) ov[e] = f2bf(lf[col][kb + e]);
        *(short8*)(o + l * 8) = *(short8*)ov;
    }
}

// ---------------- qkv bias concat (all layers) ----------------
__global__ void concat_bias_kernel(const float* __restrict__ bq, const float* __restrict__ bk,
                                   const float* __restrict__ bv, float* __restrict__ bqkv) {
    int i = blockIdx.x * 256 + threadIdx.x;
    if (i >= DEPTH * 2304) return;
    int L = i / 2304, j = i - L * 2304;
    float v = (j < 768) ? bq[L * 768 + j] : (j < 1536) ? bk[L * 768 + j - 768] : bv[L * 768 + j - 1536];
    bqkv[i] = v;
}

__global__ void cls_init_kernel(const float* __restrict__ cls,
                                const float* __restrict__ pos,
                                float* __restrict__ h) {
    int e = blockIdx.x * 256 + threadIdx.x;
    if (e < EMBED) h[e] = cls[e] + pos[e];
}

// h[1+pi] = pos[1+pi] + t0[pi] + t1[pi]  (patch-embed partial merge, rows 0..2047)
__global__ void embed_add_kernel(const float* __restrict__ pos, const float* __restrict__ t0,
                                 const float* __restrict__ t1, float* __restrict__ h) {
    int gid = blockIdx.x * 256 + threadIdx.x;
    if (gid >= 2048 * EMBED) return;
    h[EMBED + gid] = pos[EMBED + gid] + t0[gid] + t1[gid];
}

// ---------------- layernorm (plain): one block per row; packed-bf16 (nkt=24) out ----------------
template<bool PACKED>
__global__ void ln_kernel(const float* __restrict__ in, void* __restrict__ outv,
                          const float* __restrict__ w, const float* __restrict__ b,
                          int M) {
    int row = blockIdx.x;
    if (row >= M) return;
    const float* xr = in + (size_t)row * EMBED;
    int tid = threadIdx.x;
    float v0 = xr[tid], v1 = xr[tid + 256], v2 = xr[tid + 512];
    __shared__ float red[4];
    float s = v0 + v1 + v2;
    #pragma unroll
    for (int o = 32; o > 0; o >>= 1) s += __shfl_down(s, o);
    if ((tid & 63) == 0) red[tid >> 6] = s;
    __syncthreads();
    float mean = (red[0] + red[1] + red[2] + red[3]) * (1.0f / 768.0f);
    __syncthreads();
    float d0 = v0 - mean, d1 = v1 - mean, d2 = v2 - mean;
    float q2 = d0 * d0 + d1 * d1 + d2 * d2;
    #pragma unroll
    for (int o = 32; o > 0; o >>= 1) q2 += __shfl_down(q2, o);
    if ((tid & 63) == 0) red[tid >> 6] = q2;
    __syncthreads();
    float var = (red[0] + red[1] + red[2] + red[3]) * (1.0f / 768.0f);
    float rstd = 1.0f / sqrtf(var + 1e-5f);
    float o0 = d0 * rstd * w[tid]       + b[tid];
    float o1 = d1 * rstd * w[tid + 256] + b[tid + 256];
    float o2 = d2 * rstd * w[tid + 512] + b[tid + 512];
    if (PACKED) {
        unsigned short* o = (unsigned short*)outv;
        o[pidx(row, tid,       24)] = f2bf(o0);
        o[pidx(row, tid + 256, 24)] = f2bf(o1);
        o[pidx(row, tid + 512, 24)] = f2bf(o2);
    } else {
        float* orow = (float*)outv + (size_t)row * EMBED;
        orow[tid] = o0; orow[tid + 256] = o1; orow[tid + 512] = o2;
    }
}

// ---------------- layernorm + fused residual: v = h + t0 + t1; h = v; LN(v) -> out ----------
template<bool PACKED>
__global__ void ln_res_kernel(float* __restrict__ h, const float* __restrict__ t0,
                              const float* __restrict__ t1, void* __restrict__ outv,
                              const float* __restrict__ w, const float* __restrict__ b,
                              int M) {
    int row = blockIdx.x;
    if (row >= M) return;
    const size_t base = (size_t)row * EMBED;
    int tid = threadIdx.x;
    float v0 = h[base + tid]       + t0[base + tid]       + t1[base + tid];
    float v1 = h[base + tid + 256] + t0[base + tid + 256] + t1[base + tid + 256];
    float v2 = h[base + tid + 512] + t0[base + tid + 512] + t1[base + tid + 512];
    h[base + tid] = v0; h[base + tid + 256] = v1; h[base + tid + 512] = v2;
    __shared__ float red[4];
    float s = v0 + v1 + v2;
    #pragma unroll
    for (int o = 32; o > 0; o >>= 1) s += __shfl_down(s, o);
    if ((tid & 63) == 0) red[tid >> 6] = s;
    __syncthreads();
    float mean = (red[0] + red[1] + red[2] + red[3]) * (1.0f / 768.0f);
    __syncthreads();
    float d0 = v0 - mean, d1 = v1 - mean, d2 = v2 - mean;
    float q2 = d0 * d0 + d1 * d1 + d2 * d2;
    #pragma unroll
    for (int o = 32; o > 0; o >>= 1) q2 += __shfl_down(q2, o);
    if ((tid & 63) == 0) red[tid >> 6] = q2;
    __syncthreads();
    float var = (red[0] + red[1] + red[2] + red[3]) * (1.0f / 768.0f);
    float rstd = 1.0f / sqrtf(var + 1e-5f);
    float o0 = d0 * rstd * w[tid]       + b[tid];
    float o1 = d1 * rstd * w[tid + 256] + b[tid + 256];
    float o2 = d2 * rstd * w[tid + 512] + b[tid + 512];
    if (PACKED) {
        unsigned short* o = (unsigned short*)outv;
        o[pidx(row, tid,       24)] = f2bf(o0);
        o[pidx(row, tid + 256, 24)] = f2bf(o1);
        o[pidx(row, tid + 512, 24)] = f2bf(o2);
    } else {
        float* orow = (float*)outv + (size_t)row * EMBED;
        orow[tid] = o0; orow[tid + 256] = o1; orow[tid + 512] = o2;
    }
}

// ---------------- bf16 MFMA GEMM: LDS-free, fragment-packed, 128x128 block (2x2 waves) ----
// 1D grid with bijective XCD swizzle (m204), x-fastest work order for A-panel L2 locality.
// MODE 0: f32 partial store, chunk bz writes Cf + bz*SP*EMBED (N must be 768; bias chunk 0).
// MODE 2: bf16 row-major store. MODE 3: bf16 packed store. MODE 2/3 require nz == 1.
// NO ATOMICS anywhere (round-12 theory: atomic-unit throughput bound the accum GEMMs).
template<int ACT, int MODE>
__global__ __launch_bounds__(256)
void gemm_bf16(const unsigned short* __restrict__ Apk, const unsigned short* __restrict__ Bpk,
               const float* __restrict__ bias, void* __restrict__ Cv,
               int M, int N, int K, int nx, int ny, int nz) {
    // --- bijective XCD swizzle ---
    const int nwg = nx * ny * nz;
    const int fid = blockIdx.x;
    const int xcd = fid & 7, slot = fid >> 3;
    const int qq = nwg >> 3, rr2 = nwg & 7;
    const int orig = (xcd < rr2 ? xcd * (qq + 1) : rr2 * (qq + 1) + (xcd - rr2) * qq) + slot;
    const int bx = orig % nx;
    const int tzy = orig / nx;
    const int bz = tzy % nz;
    const int by = tzy / nz;

    const int tid = threadIdx.x;
    const int lane = tid & 63;
    const int w4 = tid >> 6;
    const int wm = w4 >> 1, wn = w4 & 1;
    const int row0 = by * 128 + wm * 64, col0 = bx * 128 + wn * 64;
    const int nktT = K >> 5;                       // total K tiles
    const int nk = nktT / nz;                      // tiles this chunk
    const int t0 = bz * nk;

    f32x4 acc[4][4];
    #pragma unroll
    for (int mi = 0; mi < 4; ++mi)
        #pragma unroll
        for (int ni = 0; ni < 4; ++ni)
            #pragma unroll
            for (int j = 0; j < 4; ++j) acc[mi][ni][j] = 0.0f;

    const unsigned short* Ab[4];
    const unsigned short* Bb[4];
    #pragma unroll
    for (int i = 0; i < 4; ++i) {
        Ab[i] = Apk + (((size_t)(by * 8 + wm * 4 + i) * nktT + t0) << 9) + lane * 8;
        Bb[i] = Bpk + (((size_t)(bx * 8 + wn * 4 + i) * nktT + t0) << 9) + lane * 8;
    }

    auto LOADT = [&](int t, short8* aa, short8* bb) {
        #pragma unroll
        for (int i = 0; i < 4; ++i) {
            aa[i] = *(const short8*)(Ab[i] + (size_t)t * 512);
            bb[i] = *(const short8*)(Bb[i] + (size_t)t * 512);
        }
    };
    auto MF = [&](short8* aa, short8* bb) {
        #pragma unroll
        for (int mi = 0; mi < 4; ++mi)
            #pragma unroll
            for (int ni = 0; ni < 4; ++ni)
                acc[mi][ni] = __builtin_amdgcn_mfma_f32_16x16x32_bf16(aa[mi], bb[ni], acc[mi][ni], 0, 0, 0);
    };

    short8 A0[4], B0[4], A1[4], B1[4];
    LOADT(0, A0, B0);
    for (int t = 0; t < nk; t += 2) {              // nk % 2 == 0
        LOADT(t + 1, A1, B1);
        MF(A0, B0);
        if (t + 2 < nk) LOADT(t + 2, A0, B0);
        MF(A1, B1);
    }

    float* Cf = (float*)Cv + (MODE == 0 ? (size_t)bz * SP * EMBED : 0);
    unsigned short* Cb = (unsigned short*)Cv;
    const int ln15 = lane & 15, kq = lane >> 4;
    const int nktN = N >> 5;
    const bool addb = (bz == 0);
    #pragma unroll
    for (int mi = 0; mi < 4; ++mi) {
        #pragma unroll
        for (int ni = 0; ni < 4; ++ni) {
            const int col = col0 + ni * 16 + ln15;
            const float bb = addb ? bias[col] : 0.0f;
            #pragma unroll
            for (int j = 0; j < 4; ++j) {
                const int row = row0 + mi * 16 + kq * 4 + j;
                if (row < M) {
                    float v = acc[mi][ni][j] + bb;
                    if (ACT == 1) v = 0.5f * v * (1.0f + erff(v * 0.70710678118654752f));
                    if (MODE == 0)      Cf[(size_t)row * N + col] = v;
                    else if (MODE == 2) Cb[(size_t)row * N + col] = f2bf(v);
                    else                Cb[pidx(row, col, nktN)] = f2bf(v);
                }
            }
        }
    }
}

// ---------------- dilated attention: MFMA (bf16 qkv in, bf16 Obr out) ----------------
__global__ __launch_bounds__(256, 1)
void attn_kernel(const unsigned short* __restrict__ qkv,
                 unsigned short* __restrict__ Obr, float* __restrict__ Lbr) {
    const int bx = blockIdx.x, hh = blockIdx.y;
    int b, n;
    if      (bx < 17) { b = 0; n = bx; }
    else if (bx < 26) { b = 1; n = bx - 17; }
    else if (bx < 31) { b = 2; n = bx - 26; }
    else if (bx < 34) { b = 3; n = bx - 31; }
    else              { b = 4; n = bx - 34; }
    const int r = 1 << b;
    const int segw = 128 << b;
    const int base = n * segw + (hh & (r - 1));

    __shared__ __attribute__((aligned(16))) unsigned short VT[64 * 128];   // [d][k] swizzled
    __shared__ __attribute__((aligned(16))) unsigned short Pl[128 * 128];  // [q][k] swizzled

    const int tid = threadIdx.x;

    // ---- stage V^T (transposed + swizzled) ----
    {
        const int key = tid >> 1, dh2 = (tid & 1) * 32;
        const int pos = base + r * key;
        const bool val = pos < N_REAL;
        const unsigned short* vsrc = qkv + (size_t)(val ? pos : 0) * 2304 + 1536 + hh * 64 + dh2;
        #pragma unroll
        for (int u = 0; u < 4; ++u) {
            short8 vv = ((const short8*)vsrc)[u];
            #pragma unroll
            for (int e = 0; e < 8; ++e) {
                const int d = dh2 + u * 8 + e;
                VT[(d * 256 + ((key * 2) ^ ((d & 7) << 4))) >> 1] =
                    val ? (unsigned short)vv[e] : (unsigned short)0;
            }
        }
    }
    __syncthreads();

    const int lane = tid & 63, wv = tid >> 6;
    const int ln15 = lane & 15, kq = lane >> 4;

    // ---- QK^T ----
    f32x4 sc[2][8];
    #pragma unroll
    for (int mi = 0; mi < 2; ++mi)
        #pragma unroll
        for (int ni = 0; ni < 8; ++ni)
            #pragma unroll
            for (int j = 0; j < 4; ++j) sc[mi][ni][j] = 0.0f;

    #pragma unroll
    for (int kt = 0; kt < 2; ++kt) {
        short8 qfr[2], kfr[8];
        #pragma unroll
        for (int mi = 0; mi < 2; ++mi) {
            const int pos = base + r * (wv * 32 + mi * 16 + ln15);
            qfr[mi] = *(const short8*)(qkv + (size_t)(pos < N_REAL ? pos : 0) * 2304
                                       + hh * 64 + kt * 32 + kq * 8);
        }
        #pragma unroll
        for (int ni = 0; ni < 8; ++ni) {
            const int pos = base + r * (ni * 16 + ln15);
            kfr[ni] = *(const short8*)(qkv + (size_t)(pos < N_REAL ? pos : 0) * 2304
                                       + 768 + hh * 64 + kt * 32 + kq * 8);
        }
        #pragma unroll
        for (int mi = 0; mi < 2; ++mi)
            #pragma unroll
            for (int ni = 0; ni < 8; ++ni)
                sc[mi][ni] = __builtin_amdgcn_mfma_f32_16x16x32_bf16(qfr[mi], kfr[ni], sc[mi][ni], 0, 0, 0);
    }

    // scale + key mask
    #pragma unroll
    for (int ni = 0; ni < 8; ++ni) {
        const bool kval = (base + r * (ni * 16 + ln15)) < N_REAL;
        #pragma unroll
        for (int mi = 0; mi < 2; ++mi)
            #pragma unroll
            for (int j = 0; j < 4; ++j)
                sc[mi][ni][j] = kval ? sc[mi][ni][j] * 0.125f : NEGV;
    }

    // ---- wave-local row softmax ----
    float rsum[2][4];
    #pragma unroll
    for (int mi = 0; mi < 2; ++mi) {
        #pragma unroll
        for (int j = 0; j < 4; ++j) {
            float mx = sc[mi][0][j];
            #pragma unroll
            for (int ni = 1; ni < 8; ++ni) mx = fmaxf(mx, sc[mi][ni][j]);
            mx = fmaxf(mx, __shfl_xor(mx, 1));
            mx = fmaxf(mx, __shfl_xor(mx, 2));
            mx = fmaxf(mx, __shfl_xor(mx, 4));
            mx = fmaxf(mx, __shfl_xor(mx, 8));
            float sm = 0.f;
            #pragma unroll
            for (int ni = 0; ni < 8; ++ni) {
                float e = __expf(sc[mi][ni][j] - mx);
                sc[mi][ni][j] = e;
                sm += e;
            }
            sm += __shfl_xor(sm, 1);
            sm += __shfl_xor(sm, 2);
            sm += __shfl_xor(sm, 4);
            sm += __shfl_xor(sm, 8);
            rsum[mi][j] = sm;
            const int prow = wv * 32 + mi * 16 + kq * 4 + j;
            const int qpos = base + r * prow;
            if (ln15 == 0 && qpos < N_REAL)
                Lbr[((size_t)b * SP + qpos) * HEADS + hh] = mx + logf(sm);
        }
    }

    // ---- write P to LDS (bf16, swizzled) ----
    #pragma unroll
    for (int mi = 0; mi < 2; ++mi)
        #pragma unroll
        for (int j = 0; j < 4; ++j) {
            const int prow = wv * 32 + mi * 16 + kq * 4 + j;
            #pragma unroll
            for (int ni = 0; ni < 8; ++ni) {
                const int col = ni * 16 + ln15;
                Pl[(prow * 256 + ((col * 2) ^ ((prow & 7) << 4))) >> 1] = f2bf(sc[mi][ni][j]);
            }
        }
    __syncthreads();

    // ---- PV: O[32 q][64 d] per wave, K=128 ----
    f32x4 ov[2][4];
    #pragma unroll
    for (int mi = 0; mi < 2; ++mi)
        #pragma unroll
        for (int ni = 0; ni < 4; ++ni)
            #pragma unroll
            for (int j = 0; j < 4; ++j) ov[mi][ni][j] = 0.0f;

    #pragma unroll
    for (int kt = 0; kt < 4; ++kt) {
        short8 pa[2], vb[4];
        #pragma unroll
        for (int mi = 0; mi < 2; ++mi) {
            const int row = wv * 32 + mi * 16 + ln15;
            pa[mi] = *(const short8*)((const char*)Pl + row * 256
                                      + ((kt * 64 + kq * 16) ^ ((row & 7) << 4)));
        }
        #pragma unroll
        for (int ni = 0; ni < 4; ++ni) {
            const int d = ni * 16 + ln15;
            vb[ni] = *(const short8*)((const char*)VT + d * 256
                                      + ((kt * 64 + kq * 16) ^ ((d & 7) << 4)));
        }
        #pragma unroll
        for (int mi = 0; mi < 2; ++mi)
            #pragma unroll
            for (int ni = 0; ni < 4; ++ni)
                ov[mi][ni] = __builtin_amdgcn_mfma_f32_16x16x32_bf16(pa[mi], vb[ni], ov[mi][ni], 0, 0, 0);
    }

    // ---- epilogue: normalize + store ----
    #pragma unroll
    for (int mi = 0; mi < 2; ++mi)
        #pragma unroll
        for (int j = 0; j < 4; ++j) {
            const int prow = wv * 32 + mi * 16 + kq * 4 + j;
            const int qpos = base + r * prow;
            if (qpos < N_REAL) {
                const float inv = 1.0f / rsum[mi][j];
                #pragma unroll
                for (int ni = 0; ni < 4; ++ni)
                    Obr[((size_t)b * N_REAL + qpos) * EMBED + hh * 64 + ni * 16 + ln15] =
                        f2bf(ov[mi][ni][j] * inv);
            }
        }
}

// ---------------- branch combine -> packed bf16 (A-layout, nkt=24) ----------------
__global__ void combine_kernel(const unsigned short* __restrict__ Obr, const float* __restrict__ Lbr,
                               unsigned short* __restrict__ out) {
    int gid = blockIdx.x * 256 + threadIdx.x;
    if (gid >= N_REAL * EMBED) return;
    int p = gid / EMBED, e = gid - p * EMBED;
    int h = e >> 6;
    float l[5];
    float mx = NEGV;
    #pragma unroll
    for (int b = 0; b < 5; ++b) {
        const int rm = (1 << b) - 1;
        l[b] = ((p & rm) == (h & rm)) ? Lbr[((size_t)b * SP + p) * HEADS + h] : NEGV;
        mx = fmaxf(mx, l[b]);
    }
    float wsum = 0.f, acc = 0.f;
    #pragma unroll
    for (int b = 0; b < 5; ++b) {
        if (l[b] > NEGV * 0.5f) {
            float wt = expf(l[b] - mx);
            wsum += wt;
            acc += wt * bf2f(Obr[((size_t)b * N_REAL + p) * EMBED + e]);
        }
    }
    out[pidx(p, e, 24)] = f2bf(acc / wsum);
}

// ---------------- host orchestration ----------------
extern "C" void kernel_launch(void* const* d_in, const int* in_sizes, int n_in,
                              void* d_out, int out_size, void* d_ws, size_t ws_size,
                              hipStream_t stream) {
    const float* x      = (const float*)d_in[0];
    const float* conv_w = (const float*)d_in[1];
    const float* conv_b = (const float*)d_in[2];
    const float* cls    = (const float*)d_in[3];
    const float* pos    = (const float*)d_in[4];
    const float* ln1w   = (const float*)d_in[5];
    const float* ln1b   = (const float*)d_in[6];
    const float* wq     = (const float*)d_in[7];
    const float* bq     = (const float*)d_in[8];
    const float* wk     = (const float*)d_in[9];
    const float* bk     = (const float*)d_in[10];
    const float* wv     = (const float*)d_in[11];
    const float* bv     = (const float*)d_in[12];
    const float* wo     = (const float*)d_in[13];
    const float* bo     = (const float*)d_in[14];
    const float* ln2w   = (const float*)d_in[15];
    const float* ln2b   = (const float*)d_in[16];
    const float* w1     = (const float*)d_in[17];
    const float* b1     = (const float*)d_in[18];
    const float* w2     = (const float*)d_in[19];
    const float* b2     = (const float*)d_in[20];
    const float* lnfw   = (const float*)d_in[21];
    const float* lnfb   = (const float*)d_in[22];

    float* ws = (float*)d_ws;
    // fp32 buffers
    float* h     = ws;  ws += (size_t)SP * EMBED;            // residual stream
    float* tmp0  = ws;  ws += (size_t)SP * EMBED;            // GEMM partial (chunk 0)
    float* tmp1  = ws;  ws += (size_t)SP * EMBED;            // GEMM partial (chunk 1)
    float* Lbr   = ws;  ws += (size_t)5 * SP * HEADS;
    float* bqkv  = ws;  ws += (size_t)DEPTH * 2304;
    // bf16 buffers
    unsigned short* qkv_bf   = (unsigned short*)ws;  ws += (size_t)SPAD * 2304 / 2;    // row-major (attn)
    unsigned short* xln_pk   = (unsigned short*)ws;  ws += (size_t)SPAD * EMBED / 2;   // packed A
    unsigned short* attn_pk  = (unsigned short*)ws;  ws += (size_t)SPAD * EMBED / 2;   // packed A
    unsigned short* mid_pk   = (unsigned short*)ws;  ws += (size_t)SPAD * MLP_DIM / 2; // packed A
    unsigned short* patch_pk = (unsigned short*)ws;  ws += (size_t)2112 * 1024 / 2;    // packed A
    unsigned short* convw_pk = (unsigned short*)ws;  ws += (size_t)EMBED * 1024 / 2;   // packed B
    unsigned short* Obr      = (unsigned short*)ws;  ws += (size_t)5 * N_REAL * EMBED / 2 + 64;
    unsigned short* wqkv_pk  = (unsigned short*)ws;  ws += (size_t)2304 * EMBED / 2;   // packed B
    unsigned short* wo_pk    = (unsigned short*)ws;  ws += (size_t)EMBED * EMBED / 2;  // packed B
    unsigned short* w1_pk    = (unsigned short*)ws;  ws += (size_t)MLP_DIM * EMBED / 2;// packed B
    unsigned short* w2_pk    = (unsigned short*)ws;  ws += (size_t)EMBED * MLP_DIM / 2;// packed B

    // ---- embed ----
    im2col_kernel<<<2048, 256, 0, stream>>>(x, patch_pk);
    pack_NK_kernel<<<dim3(6, 32), 256, 0, stream>>>(conv_w, convw_pk, EMBED, 1024);
    concat_bias_kernel<<<(DEPTH * 2304 + 255) / 256, 256, 0, stream>>>(bq, bk, bv, bqkv);
    cls_init_kernel<<<3, 256, 0, stream>>>(cls, pos, h);
    // patch GEMM -> two f32 partials (nx=6, ny=16, nz=2; 192 blocks), then merge with pos
    gemm_bf16<0, 0><<<192, 256, 0, stream>>>(patch_pk, convw_pk, conv_b,
                                             tmp0, 2048, EMBED, 1024, 6, 16, 2);
    embed_add_kernel<<<(2048 * EMBED + 255) / 256, 256, 0, stream>>>(pos, tmp0, tmp1, h);

    for (int L = 0; L < DEPTH; ++L) {
        const size_t EE = (size_t)EMBED * EMBED;
        const size_t EM = (size_t)EMBED * MLP_DIM;
        // all weight packing for this layer in ONE launch (1728 blocks)
        pack_all_kernel<<<1728, 256, 0, stream>>>(wq + L * EE, wk + L * EE, wv + L * EE,
                                                  wo + L * EE, w1 + L * EM, w2 + L * EM,
                                                  wqkv_pk, wo_pk, w1_pk, w2_pk);

        // LN1 -> packed bf16 (layer 0: h final; layers 1..5: fold in prev MLP2 partials)
        if (L == 0)
            ln_kernel<true><<<N_REAL, 256, 0, stream>>>(h, xln_pk, ln1w + (size_t)L * EMBED,
                                                        ln1b + (size_t)L * EMBED, N_REAL);
        else
            ln_res_kernel<true><<<N_REAL, 256, 0, stream>>>(h, tmp0, tmp1, xln_pk,
                                                            ln1w + (size_t)L * EMBED,
                                                            ln1b + (size_t)L * EMBED, N_REAL);
        // fused QKV -> row-major bf16 (nx=18, ny=17, nz=1 -> 306 blocks)
        gemm_bf16<0, 2><<<306, 256, 0, stream>>>(xln_pk, wqkv_pk, bqkv + (size_t)L * 2304,
                                                 qkv_bf, N_REAL, 2304, EMBED, 18, 17, 1);
        // dilated attention (MFMA)
        attn_kernel<<<dim3(36, 12), 256, 0, stream>>>(qkv_bf, Obr, Lbr);
        combine_kernel<<<((N_REAL * EMBED) + 255) / 256, 256, 0, stream>>>(Obr, Lbr, attn_pk);
        // O-projection -> two f32 partials (nx=6, ny=17, nz=2 -> 204 blocks)
        gemm_bf16<0, 0><<<204, 256, 0, stream>>>(attn_pk, wo_pk, bo + (size_t)L * EMBED,
                                                 tmp0, N_REAL, EMBED, EMBED, 6, 17, 2);
        // LN2 folds O-proj partials into h -> packed bf16
        ln_res_kernel<true><<<N_REAL, 256, 0, stream>>>(h, tmp0, tmp1, xln_pk,
                                                        ln2w + (size_t)L * EMBED,
                                                        ln2b + (size_t)L * EMBED, N_REAL);
        gemm_bf16<1, 3><<<408, 256, 0, stream>>>(xln_pk, w1_pk, b1 + (size_t)L * MLP_DIM,
                                                 mid_pk, N_REAL, MLP_DIM, EMBED, 24, 17, 1);
        // MLP2 -> two f32 partials (folded by next LN1 / final LN)
        gemm_bf16<0, 0><<<204, 256, 0, stream>>>(mid_pk, w2_pk, b2 + (size_t)L * EMBED,
                                                 tmp0, N_REAL, EMBED, MLP_DIM, 6, 17, 2);
    }

    // final LN on row 0 (folds last MLP2 partials) -> d_out (768 fp32)
    ln_res_kernel<false><<<1, 256, 0, stream>>>(h, tmp0, tmp1, (float*)d_out, lnfw, lnfb, 1);
}

// Round 16
// 929.575 us; speedup vs baseline: 1.0081x; 1.0081x over previous
//
#include <hip/hip_runtime.h>
#include <math.h>

#define EMBED 768
#define HEADS 12
#define DH 64
#define DEPTH 6
#define MLP_DIM 3072
#define N_REAL 2049
#define SP 2112            // fp32 buffer row padding (33*64)
#define SPAD 2176          // bf16 activation row padding (17*128)
#define NEGV (-1e9f)

typedef __attribute__((ext_vector_type(8))) short short8;
typedef __attribute__((ext_vector_type(4))) float f32x4;

__device__ __forceinline__ unsigned short f2bf(float f) {
    union { float f; unsigned u; } x; x.f = f;
    unsigned r = x.u + 0x7FFF + ((x.u >> 16) & 1);
    return (unsigned short)(r >> 16);
}
__device__ __forceinline__ float bf2f(unsigned short s) {
    union { unsigned u; float f; } x; x.u = (unsigned)s << 16;
    return x.f;
}

// packed fragment-blob index: blobs of 16 "major" (row for A / col for B) x 32 k.
// entry (l*8+e) of blob = element (major = l&15, k = (l>>4)*8 + e).
__device__ __forceinline__ size_t pidx(int mj, int k, int nkt) {
    return (((size_t)(mj >> 4) * nkt + (k >> 5)) << 9) + (size_t)((((k >> 3) & 3) * 16 + (mj & 15)) * 8 + (k & 7));
}

// ---------------- im2col: x -> packed patch blobs (A-layout, nkt=32) ----------------
__global__ void im2col_kernel(const float* __restrict__ x, unsigned short* __restrict__ p) {
    const int pi = blockIdx.x;            // 0..2047
    const int d = pi >> 8, rr = (pi >> 4) & 15, cc = pi & 15;
    const int t = threadIdx.x;            // 256
    #pragma unroll
    for (int u = 0; u < 4; ++u) {
        int i = u * 256 + t;              // 0..1023
        int kd = i >> 8, kr = (i >> 4) & 15, kc = i & 15;
        float v = x[(size_t)(d * 4 + kd) * 65536 + (rr * 16 + kr) * 256 + (cc * 16 + kc)];
        p[pidx(pi, i, 32)] = f2bf(v);
    }
}

// ---------------- weight pack: fp32 [K][N] -> fragment blobs (B-layout) ----------------
__device__ __forceinline__ void pack_KN_body(const float* __restrict__ src,
                                             unsigned short* __restrict__ dst,
                                             int N, int K, int bn, int bk) {
    __shared__ float lf[128][33];         // [n][k]
    const int t = threadIdx.x;
    {
        const int kk = t >> 3, ch = t & 7;
        const float4* s = (const float4*)(src + (size_t)(bk * 32 + kk) * N + bn * 128 + ch * 16);
        float4 v0 = s[0], v1 = s[1], v2 = s[2], v3 = s[3];
        float tmp[16];
        ((float4*)tmp)[0] = v0; ((float4*)tmp)[1] = v1; ((float4*)tmp)[2] = v2; ((float4*)tmp)[3] = v3;
        #pragma unroll
        for (int u = 0; u < 16; ++u) lf[ch * 16 + u][kk] = tmp[u];
    }
    __syncthreads();
    const int nkt = K >> 5;
    const int cg = t >> 5;                // blob 0..7
    const int l0 = (t & 31) * 2;
    unsigned short* o = dst + (((size_t)(bn * 8 + cg) * nkt + bk) << 9);
    #pragma unroll
    for (int q = 0; q < 2; ++q) {
        const int l = l0 + q;
        const int col = cg * 16 + (l & 15), kb = (l >> 4) * 8;
        unsigned short ov[8];
        #pragma unroll
        for (int e = 0; e < 8; ++e) ov[e] = f2bf(lf[col][kb + e]);
        *(short8*)(o + l * 8) = *(short8*)ov;
    }
}

// one launch packs a whole layer: 4x[768][768] (576 blocks) + w1 (576) + w2 (576)
__global__ void pack_all_kernel(const float* __restrict__ wq, const float* __restrict__ wk,
                                const float* __restrict__ wv, const float* __restrict__ wo,
                                const float* __restrict__ w1s, const float* __restrict__ w2s,
                                unsigned short* __restrict__ qkv_pk, unsigned short* __restrict__ o_pk,
                                unsigned short* __restrict__ w1_pk, unsigned short* __restrict__ w2_pk) {
    const int fid = blockIdx.x;
    if (fid < 576) {
        const int m = fid / 144, r = fid % 144;
        const float* src = (m == 0) ? wq : (m == 1) ? wk : (m == 2) ? wv : wo;
        unsigned short* dst = (m < 3) ? qkv_pk + (size_t)m * EMBED * EMBED : o_pk;
        pack_KN_body(src, dst, EMBED, EMBED, r % 6, r / 6);
    } else if (fid < 1152) {
        const int r = fid - 576;
        pack_KN_body(w1s, w1_pk, MLP_DIM, EMBED, r % 24, r / 24);
    } else {
        const int r = fid - 1152;
        pack_KN_body(w2s, w2_pk, EMBED, MLP_DIM, r % 6, r / 6);
    }
}

// pack from fp32 [N][K] (conv_w: [768][1024])
__global__ void pack_NK_kernel(const float* __restrict__ src, unsigned short* __restrict__ dst,
                               int N, int K) {
    __shared__ float lf[128][33];
    const int bn = blockIdx.x, bk = blockIdx.y;
    const int t = threadIdx.x;
    {
        const int row = t >> 1, hf = t & 1;
        const float4* s = (const float4*)(src + (size_t)(bn * 128 + row) * K + bk * 32 + hf * 16);
        float4 v0 = s[0], v1 = s[1], v2 = s[2], v3 = s[3];
        float tmp[16];
        ((float4*)tmp)[0] = v0; ((float4*)tmp)[1] = v1; ((float4*)tmp)[2] = v2; ((float4*)tmp)[3] = v3;
        #pragma unroll
        for (int u = 0; u < 16; ++u) lf[row][hf * 16 + u] = tmp[u];
    }
    __syncthreads();
    const int nkt = K >> 5;
    const int cg = t >> 5;
    const int l0 = (t & 31) * 2;
    unsigned short* o = dst + (((size_t)(bn * 8 + cg) * nkt + bk) << 9);
    #pragma unroll
    for (int q = 0; q < 2; ++q) {
        const int l = l0 + q;
        const int col = cg * 16 + (l & 15), kb = (l >> 4) * 8;
        unsigned short ov[8];
        #pragma unroll
        for (int e = 0; e < 8; ++e) ov[e] = f2bf(lf[col][kb + e]);
        *(short8*)(o + l * 8) = *(short8*)ov;
    }
}

// ---------------- qkv bias concat (all layers) ----------------
__global__ void concat_bias_kernel(const float* __restrict__ bq, const float* __restrict__ bk,
                                   const float* __restrict__ bv, float* __restrict__ bqkv) {
    int i = blockIdx.x * 256 + threadIdx.x;
    if (i >= DEPTH * 2304) return;
    int L = i / 2304, j = i - L * 2304;
    float v = (j < 768) ? bq[L * 768 + j] : (j < 1536) ? bk[L * 768 + j - 768] : bv[L * 768 + j - 1536];
    bqkv[i] = v;
}

__global__ void cls_init_kernel(const float* __restrict__ cls,
                                const float* __restrict__ pos,
                                float* __restrict__ h) {
    int e = blockIdx.x * 256 + threadIdx.x;
    if (e < EMBED) h[e] = cls[e] + pos[e];
}

// h[1+pi] = pos[1+pi] + sum_{c<4} tmp[c][pi]  (patch-embed partial merge)
__global__ void embed_add_kernel(const float* __restrict__ pos, const float* __restrict__ tmp,
                                 float* __restrict__ h) {
    int gid = blockIdx.x * 256 + threadIdx.x;
    if (gid >= 2048 * EMBED) return;
    float v = pos[EMBED + gid];
    #pragma unroll
    for (int c = 0; c < 4; ++c) v += tmp[(size_t)c * SP * EMBED + gid];
    h[EMBED + gid] = v;
}

// ---------------- layernorm (plain): one block per row; packed-bf16 (nkt=24) out ----------------
template<bool PACKED>
__global__ void ln_kernel(const float* __restrict__ in, void* __restrict__ outv,
                          const float* __restrict__ w, const float* __restrict__ b,
                          int M) {
    int row = blockIdx.x;
    if (row >= M) return;
    const float* xr = in + (size_t)row * EMBED;
    int tid = threadIdx.x;
    float v0 = xr[tid], v1 = xr[tid + 256], v2 = xr[tid + 512];
    __shared__ float red[4];
    float s = v0 + v1 + v2;
    #pragma unroll
    for (int o = 32; o > 0; o >>= 1) s += __shfl_down(s, o);
    if ((tid & 63) == 0) red[tid >> 6] = s;
    __syncthreads();
    float mean = (red[0] + red[1] + red[2] + red[3]) * (1.0f / 768.0f);
    __syncthreads();
    float d0 = v0 - mean, d1 = v1 - mean, d2 = v2 - mean;
    float q2 = d0 * d0 + d1 * d1 + d2 * d2;
    #pragma unroll
    for (int o = 32; o > 0; o >>= 1) q2 += __shfl_down(q2, o);
    if ((tid & 63) == 0) red[tid >> 6] = q2;
    __syncthreads();
    float var = (red[0] + red[1] + red[2] + red[3]) * (1.0f / 768.0f);
    float rstd = 1.0f / sqrtf(var + 1e-5f);
    float o0 = d0 * rstd * w[tid]       + b[tid];
    float o1 = d1 * rstd * w[tid + 256] + b[tid + 256];
    float o2 = d2 * rstd * w[tid + 512] + b[tid + 512];
    if (PACKED) {
        unsigned short* o = (unsigned short*)outv;
        o[pidx(row, tid,       24)] = f2bf(o0);
        o[pidx(row, tid + 256, 24)] = f2bf(o1);
        o[pidx(row, tid + 512, 24)] = f2bf(o2);
    } else {
        float* orow = (float*)outv + (size_t)row * EMBED;
        orow[tid] = o0; orow[tid + 256] = o1; orow[tid + 512] = o2;
    }
}

// ---------------- layernorm + fused residual: v = h + sum_{c<nt} tmp[c]; h = v; LN(v) ----------
template<bool PACKED>
__global__ void ln_res_kernel(float* __restrict__ h, const float* __restrict__ tmp, int nt,
                              void* __restrict__ outv,
                              const float* __restrict__ w, const float* __restrict__ b,
                              int M) {
    int row = blockIdx.x;
    if (row >= M) return;
    const size_t base = (size_t)row * EMBED;
    int tid = threadIdx.x;
    float v0 = h[base + tid], v1 = h[base + tid + 256], v2 = h[base + tid + 512];
    for (int c = 0; c < nt; ++c) {
        const float* tc = tmp + (size_t)c * SP * EMBED + base;
        v0 += tc[tid]; v1 += tc[tid + 256]; v2 += tc[tid + 512];
    }
    h[base + tid] = v0; h[base + tid + 256] = v1; h[base + tid + 512] = v2;
    __shared__ float red[4];
    float s = v0 + v1 + v2;
    #pragma unroll
    for (int o = 32; o > 0; o >>= 1) s += __shfl_down(s, o);
    if ((tid & 63) == 0) red[tid >> 6] = s;
    __syncthreads();
    float mean = (red[0] + red[1] + red[2] + red[3]) * (1.0f / 768.0f);
    __syncthreads();
    float d0 = v0 - mean, d1 = v1 - mean, d2 = v2 - mean;
    float q2 = d0 * d0 + d1 * d1 + d2 * d2;
    #pragma unroll
    for (int o = 32; o > 0; o >>= 1) q2 += __shfl_down(q2, o);
    if ((tid & 63) == 0) red[tid >> 6] = q2;
    __syncthreads();
    float var = (red[0] + red[1] + red[2] + red[3]) * (1.0f / 768.0f);
    float rstd = 1.0f / sqrtf(var + 1e-5f);
    float o0 = d0 * rstd * w[tid]       + b[tid];
    float o1 = d1 * rstd * w[tid + 256] + b[tid + 256];
    float o2 = d2 * rstd * w[tid + 512] + b[tid + 512];
    if (PACKED) {
        unsigned short* o = (unsigned short*)outv;
        o[pidx(row, tid,       24)] = f2bf(o0);
        o[pidx(row, tid + 256, 24)] = f2bf(o1);
        o[pidx(row, tid + 512, 24)] = f2bf(o2);
    } else {
        float* orow = (float*)outv + (size_t)row * EMBED;
        orow[tid] = o0; orow[tid + 256] = o1; orow[tid + 512] = o2;
    }
}

// ---------------- bf16 MFMA GEMM: LDS-free, fragment-packed, 128x128 block (2x2 waves) ----
// 1D grid with bijective XCD swizzle (m204), x-fastest work order for A-panel L2 locality.
// MODE 0: f32 partial store, chunk bz writes Cf + bz*SP*EMBED (N must be 768; bias chunk 0).
// MODE 2: bf16 row-major store. MODE 3: bf16 packed store. MODE 2/3 require nz == 1.
// No atomics (round-12/15: atomic-unit throughput was binding the accum GEMMs).
template<int ACT, int MODE>
__global__ __launch_bounds__(256)
void gemm_bf16(const unsigned short* __restrict__ Apk, const unsigned short* __restrict__ Bpk,
               const float* __restrict__ bias, void* __restrict__ Cv,
               int M, int N, int K, int nx, int ny, int nz) {
    // --- bijective XCD swizzle ---
    const int nwg = nx * ny * nz;
    const int fid = blockIdx.x;
    const int xcd = fid & 7, slot = fid >> 3;
    const int qq = nwg >> 3, rr2 = nwg & 7;
    const int orig = (xcd < rr2 ? xcd * (qq + 1) : rr2 * (qq + 1) + (xcd - rr2) * qq) + slot;
    const int bx = orig % nx;
    const int tzy = orig / nx;
    const int bz = tzy % nz;
    const int by = tzy / nz;

    const int tid = threadIdx.x;
    const int lane = tid & 63;
    const int w4 = tid >> 6;
    const int wm = w4 >> 1, wn = w4 & 1;
    const int row0 = by * 128 + wm * 64, col0 = bx * 128 + wn * 64;
    const int nktT = K >> 5;                       // total K tiles
    const int nk = nktT / nz;                      // tiles this chunk
    const int t0 = bz * nk;

    f32x4 acc[4][4];
    #pragma unroll
    for (int mi = 0; mi < 4; ++mi)
        #pragma unroll
        for (int ni = 0; ni < 4; ++ni)
            #pragma unroll
            for (int j = 0; j < 4; ++j) acc[mi][ni][j] = 0.0f;

    const unsigned short* Ab[4];
    const unsigned short* Bb[4];
    #pragma unroll
    for (int i = 0; i < 4; ++i) {
        Ab[i] = Apk + (((size_t)(by * 8 + wm * 4 + i) * nktT + t0) << 9) + lane * 8;
        Bb[i] = Bpk + (((size_t)(bx * 8 + wn * 4 + i) * nktT + t0) << 9) + lane * 8;
    }

    auto LOADT = [&](int t, short8* aa, short8* bb) {
        #pragma unroll
        for (int i = 0; i < 4; ++i) {
            aa[i] = *(const short8*)(Ab[i] + (size_t)t * 512);
            bb[i] = *(const short8*)(Bb[i] + (size_t)t * 512);
        }
    };
    auto MF = [&](short8* aa, short8* bb) {
        #pragma unroll
        for (int mi = 0; mi < 4; ++mi)
            #pragma unroll
            for (int ni = 0; ni < 4; ++ni)
                acc[mi][ni] = __builtin_amdgcn_mfma_f32_16x16x32_bf16(aa[mi], bb[ni], acc[mi][ni], 0, 0, 0);
    };

    short8 A0[4], B0[4], A1[4], B1[4];
    LOADT(0, A0, B0);
    for (int t = 0; t < nk; t += 2) {              // nk % 2 == 0
        LOADT(t + 1, A1, B1);
        MF(A0, B0);
        if (t + 2 < nk) LOADT(t + 2, A0, B0);
        MF(A1, B1);
    }

    float* Cf = (float*)Cv + (MODE == 0 ? (size_t)bz * SP * EMBED : 0);
    unsigned short* Cb = (unsigned short*)Cv;
    const int ln15 = lane & 15, kq = lane >> 4;
    const int nktN = N >> 5;
    const bool addb = (bz == 0);
    #pragma unroll
    for (int mi = 0; mi < 4; ++mi) {
        #pragma unroll
        for (int ni = 0; ni < 4; ++ni) {
            const int col = col0 + ni * 16 + ln15;
            const float bb = addb ? bias[col] : 0.0f;
            #pragma unroll
            for (int j = 0; j < 4; ++j) {
                const int row = row0 + mi * 16 + kq * 4 + j;
                if (row < M) {
                    float v = acc[mi][ni][j] + bb;
                    if (ACT == 1) v = 0.5f * v * (1.0f + erff(v * 0.70710678118654752f));
                    if (MODE == 0)      Cf[(size_t)row * N + col] = v;
                    else if (MODE == 2) Cb[(size_t)row * N + col] = f2bf(v);
                    else                Cb[pidx(row, col, nktN)] = f2bf(v);
                }
            }
        }
    }
}

// ---------------- dilated attention: MFMA (bf16 qkv in, bf16 Obr out) ----------------
__global__ __launch_bounds__(256, 1)
void attn_kernel(const unsigned short* __restrict__ qkv,
                 unsigned short* __restrict__ Obr, float* __restrict__ Lbr) {
    const int bx = blockIdx.x, hh = blockIdx.y;
    int b, n;
    if      (bx < 17) { b = 0; n = bx; }
    else if (bx < 26) { b = 1; n = bx - 17; }
    else if (bx < 31) { b = 2; n = bx - 26; }
    else if (bx < 34) { b = 3; n = bx - 31; }
    else              { b = 4; n = bx - 34; }
    const int r = 1 << b;
    const int segw = 128 << b;
    const int base = n * segw + (hh & (r - 1));

    __shared__ __attribute__((aligned(16))) unsigned short VT[64 * 128];   // [d][k] swizzled
    __shared__ __attribute__((aligned(16))) unsigned short Pl[128 * 128];  // [q][k] swizzled

    const int tid = threadIdx.x;

    // ---- stage V^T (transposed + swizzled) ----
    {
        const int key = tid >> 1, dh2 = (tid & 1) * 32;
        const int pos = base + r * key;
        const bool val = pos < N_REAL;
        const unsigned short* vsrc = qkv + (size_t)(val ? pos : 0) * 2304 + 1536 + hh * 64 + dh2;
        #pragma unroll
        for (int u = 0; u < 4; ++u) {
            short8 vv = ((const short8*)vsrc)[u];
            #pragma unroll
            for (int e = 0; e < 8; ++e) {
                const int d = dh2 + u * 8 + e;
                VT[(d * 256 + ((key * 2) ^ ((d & 7) << 4))) >> 1] =
                    val ? (unsigned short)vv[e] : (unsigned short)0;
            }
        }
    }
    __syncthreads();

    const int lane = tid & 63, wv = tid >> 6;
    const int ln15 = lane & 15, kq = lane >> 4;

    // ---- QK^T ----
    f32x4 sc[2][8];
    #pragma unroll
    for (int mi = 0; mi < 2; ++mi)
        #pragma unroll
        for (int ni = 0; ni < 8; ++ni)
            #pragma unroll
            for (int j = 0; j < 4; ++j) sc[mi][ni][j] = 0.0f;

    #pragma unroll
    for (int kt = 0; kt < 2; ++kt) {
        short8 qfr[2], kfr[8];
        #pragma unroll
        for (int mi = 0; mi < 2; ++mi) {
            const int pos = base + r * (wv * 32 + mi * 16 + ln15);
            qfr[mi] = *(const short8*)(qkv + (size_t)(pos < N_REAL ? pos : 0) * 2304
                                       + hh * 64 + kt * 32 + kq * 8);
        }
        #pragma unroll
        for (int ni = 0; ni < 8; ++ni) {
            const int pos = base + r * (ni * 16 + ln15);
            kfr[ni] = *(const short8*)(qkv + (size_t)(pos < N_REAL ? pos : 0) * 2304
                                       + 768 + hh * 64 + kt * 32 + kq * 8);
        }
        #pragma unroll
        for (int mi = 0; mi < 2; ++mi)
            #pragma unroll
            for (int ni = 0; ni < 8; ++ni)
                sc[mi][ni] = __builtin_amdgcn_mfma_f32_16x16x32_bf16(qfr[mi], kfr[ni], sc[mi][ni], 0, 0, 0);
    }

    // scale + key mask
    #pragma unroll
    for (int ni = 0; ni < 8; ++ni) {
        const bool kval = (base + r * (ni * 16 + ln15)) < N_REAL;
        #pragma unroll
        for (int mi = 0; mi < 2; ++mi)
            #pragma unroll
            for (int j = 0; j < 4; ++j)
                sc[mi][ni][j] = kval ? sc[mi][ni][j] * 0.125f : NEGV;
    }

    // ---- wave-local row softmax ----
    float rsum[2][4];
    #pragma unroll
    for (int mi = 0; mi < 2; ++mi) {
        #pragma unroll
        for (int j = 0; j < 4; ++j) {
            float mx = sc[mi][0][j];
            #pragma unroll
            for (int ni = 1; ni < 8; ++ni) mx = fmaxf(mx, sc[mi][ni][j]);
            mx = fmaxf(mx, __shfl_xor(mx, 1));
            mx = fmaxf(mx, __shfl_xor(mx, 2));
            mx = fmaxf(mx, __shfl_xor(mx, 4));
            mx = fmaxf(mx, __shfl_xor(mx, 8));
            float sm = 0.f;
            #pragma unroll
            for (int ni = 0; ni < 8; ++ni) {
                float e = __expf(sc[mi][ni][j] - mx);
                sc[mi][ni][j] = e;
                sm += e;
            }
            sm += __shfl_xor(sm, 1);
            sm += __shfl_xor(sm, 2);
            sm += __shfl_xor(sm, 4);
            sm += __shfl_xor(sm, 8);
            rsum[mi][j] = sm;
            const int prow = wv * 32 + mi * 16 + kq * 4 + j;
            const int qpos = base + r * prow;
            if (ln15 == 0 && qpos < N_REAL)
                Lbr[((size_t)b * SP + qpos) * HEADS + hh] = mx + logf(sm);
        }
    }

    // ---- write P to LDS (bf16, swizzled) ----
    #pragma unroll
    for (int mi = 0; mi < 2; ++mi)
        #pragma unroll
        for (int j = 0; j < 4; ++j) {
            const int prow = wv * 32 + mi * 16 + kq * 4 + j;
            #pragma unroll
            for (int ni = 0; ni < 8; ++ni) {
                const int col = ni * 16 + ln15;
                Pl[(prow * 256 + ((col * 2) ^ ((prow & 7) << 4))) >> 1] = f2bf(sc[mi][ni][j]);
            }
        }
    __syncthreads();

    // ---- PV: O[32 q][64 d] per wave, K=128 ----
    f32x4 ov[2][4];
    #pragma unroll
    for (int mi = 0; mi < 2; ++mi)
        #pragma unroll
        for (int ni = 0; ni < 4; ++ni)
            #pragma unroll
            for (int j = 0; j < 4; ++j) ov[mi][ni][j] = 0.0f;

    #pragma unroll
    for (int kt = 0; kt < 4; ++kt) {
        short8 pa[2], vb[4];
        #pragma unroll
        for (int mi = 0; mi < 2; ++mi) {
            const int row = wv * 32 + mi * 16 + ln15;
            pa[mi] = *(const short8*)((const char*)Pl + row * 256
                                      + ((kt * 64 + kq * 16) ^ ((row & 7) << 4)));
        }
        #pragma unroll
        for (int ni = 0; ni < 4; ++ni) {
            const int d = ni * 16 + ln15;
            vb[ni] = *(const short8*)((const char*)VT + d * 256
                                      + ((kt * 64 + kq * 16) ^ ((d & 7) << 4)));
        }
        #pragma unroll
        for (int mi = 0; mi < 2; ++mi)
            #pragma unroll
            for (int ni = 0; ni < 4; ++ni)
                ov[mi][ni] = __builtin_amdgcn_mfma_f32_16x16x32_bf16(pa[mi], vb[ni], ov[mi][ni], 0, 0, 0);
    }

    // ---- epilogue: normalize + store ----
    #pragma unroll
    for (int mi = 0; mi < 2; ++mi)
        #pragma unroll
        for (int j = 0; j < 4; ++j) {
            const int prow = wv * 32 + mi * 16 + kq * 4 + j;
            const int qpos = base + r * prow;
            if (qpos < N_REAL) {
                const float inv = 1.0f / rsum[mi][j];
                #pragma unroll
                for (int ni = 0; ni < 4; ++ni)
                    Obr[((size_t)b * N_REAL + qpos) * EMBED + hh * 64 + ni * 16 + ln15] =
                        f2bf(ov[mi][ni][j] * inv);
            }
        }
}

// ---------------- branch combine -> packed bf16 (A-layout, nkt=24) ----------------
__global__ void combine_kernel(const unsigned short* __restrict__ Obr, const float* __restrict__ Lbr,
                               unsigned short* __restrict__ out) {
    int gid = blockIdx.x * 256 + threadIdx.x;
    if (gid >= N_REAL * EMBED) return;
    int p = gid / EMBED, e = gid - p * EMBED;
    int h = e >> 6;
    float l[5];
    float mx = NEGV;
    #pragma unroll
    for (int b = 0; b < 5; ++b) {
        const int rm = (1 << b) - 1;
        l[b] = ((p & rm) == (h & rm)) ? Lbr[((size_t)b * SP + p) * HEADS + h] : NEGV;
        mx = fmaxf(mx, l[b]);
    }
    float wsum = 0.f, acc = 0.f;
    #pragma unroll
    for (int b = 0; b < 5; ++b) {
        if (l[b] > NEGV * 0.5f) {
            float wt = expf(l[b] - mx);
            wsum += wt;
            acc += wt * bf2f(Obr[((size_t)b * N_REAL + p) * EMBED + e]);
        }
    }
    out[pidx(p, e, 24)] = f2bf(acc / wsum);
}

// ---------------- host orchestration ----------------
extern "C" void kernel_launch(void* const* d_in, const int* in_sizes, int n_in,
                              void* d_out, int out_size, void* d_ws, size_t ws_size,
                              hipStream_t stream) {
    const float* x      = (const float*)d_in[0];
    const float* conv_w = (const float*)d_in[1];
    const float* conv_b = (const float*)d_in[2];
    const float* cls    = (const float*)d_in[3];
    const float* pos    = (const float*)d_in[4];
    const float* ln1w   = (const float*)d_in[5];
    const float* ln1b   = (const float*)d_in[6];
    const float* wq     = (const float*)d_in[7];
    const float* bq     = (const float*)d_in[8];
    const float* wk     = (const float*)d_in[9];
    const float* bk     = (const float*)d_in[10];
    const float* wv     = (const float*)d_in[11];
    const float* bv     = (const float*)d_in[12];
    const float* wo     = (const float*)d_in[13];
    const float* bo     = (const float*)d_in[14];
    const float* ln2w   = (const float*)d_in[15];
    const float* ln2b   = (const float*)d_in[16];
    const float* w1     = (const float*)d_in[17];
    const float* b1     = (const float*)d_in[18];
    const float* w2     = (const float*)d_in[19];
    const float* b2     = (const float*)d_in[20];
    const float* lnfw   = (const float*)d_in[21];
    const float* lnfb   = (const float*)d_in[22];

    float* ws = (float*)d_ws;
    // fp32 buffers
    float* h     = ws;  ws += (size_t)SP * EMBED;            // residual stream
    float* tmp   = ws;  ws += (size_t)4 * SP * EMBED;        // GEMM partials (4 chunks)
    float* Lbr   = ws;  ws += (size_t)5 * SP * HEADS;
    float* bqkv  = ws;  ws += (size_t)DEPTH * 2304;
    // bf16 buffers
    unsigned short* qkv_bf   = (unsigned short*)ws;  ws += (size_t)SPAD * 2304 / 2;    // row-major (attn)
    unsigned short* xln_pk   = (unsigned short*)ws;  ws += (size_t)SPAD * EMBED / 2;   // packed A
    unsigned short* attn_pk  = (unsigned short*)ws;  ws += (size_t)SPAD * EMBED / 2;   // packed A
    unsigned short* mid_pk   = (unsigned short*)ws;  ws += (size_t)SPAD * MLP_DIM / 2; // packed A
    unsigned short* patch_pk = (unsigned short*)ws;  ws += (size_t)2112 * 1024 / 2;    // packed A
    unsigned short* convw_pk = (unsigned short*)ws;  ws += (size_t)EMBED * 1024 / 2;   // packed B
    unsigned short* Obr      = (unsigned short*)ws;  ws += (size_t)5 * N_REAL * EMBED / 2 + 64;
    unsigned short* wqkv_pk  = (unsigned short*)ws;  ws += (size_t)2304 * EMBED / 2;   // packed B
    unsigned short* wo_pk    = (unsigned short*)ws;  ws += (size_t)EMBED * EMBED / 2;  // packed B
    unsigned short* w1_pk    = (unsigned short*)ws;  ws += (size_t)MLP_DIM * EMBED / 2;// packed B
    unsigned short* w2_pk    = (unsigned short*)ws;  ws += (size_t)EMBED * MLP_DIM / 2;// packed B

    // ---- embed ----
    im2col_kernel<<<2048, 256, 0, stream>>>(x, patch_pk);
    pack_NK_kernel<<<dim3(6, 32), 256, 0, stream>>>(conv_w, convw_pk, EMBED, 1024);
    concat_bias_kernel<<<(DEPTH * 2304 + 255) / 256, 256, 0, stream>>>(bq, bk, bv, bqkv);
    cls_init_kernel<<<3, 256, 0, stream>>>(cls, pos, h);
    // patch GEMM -> 4 f32 partials (nx=6, ny=16, nz=4; 384 blocks), then merge with pos
    gemm_bf16<0, 0><<<384, 256, 0, stream>>>(patch_pk, convw_pk, conv_b,
                                             tmp, 2048, EMBED, 1024, 6, 16, 4);
    embed_add_kernel<<<(2048 * EMBED + 255) / 256, 256, 0, stream>>>(pos, tmp, h);

    for (int L = 0; L < DEPTH; ++L) {
        const size_t EE = (size_t)EMBED * EMBED;
        const size_t EM = (size_t)EMBED * MLP_DIM;
        // all weight packing for this layer in ONE launch (1728 blocks)
        pack_all_kernel<<<1728, 256, 0, stream>>>(wq + L * EE, wk + L * EE, wv + L * EE,
                                                  wo + L * EE, w1 + L * EM, w2 + L * EM,
                                                  wqkv_pk, wo_pk, w1_pk, w2_pk);

        // LN1 -> packed bf16 (layer 0: h final; layers 1..5: fold prev MLP2's 4 partials)
        if (L == 0)
            ln_kernel<true><<<N_REAL, 256, 0, stream>>>(h, xln_pk, ln1w + (size_t)L * EMBED,
                                                        ln1b + (size_t)L * EMBED, N_REAL);
        else
            ln_res_kernel<true><<<N_REAL, 256, 0, stream>>>(h, tmp, 4, xln_pk,
                                                            ln1w + (size_t)L * EMBED,
                                                            ln1b + (size_t)L * EMBED, N_REAL);
        // fused QKV -> row-major bf16 (nx=18, ny=17, nz=1 -> 306 blocks)
        gemm_bf16<0, 2><<<306, 256, 0, stream>>>(xln_pk, wqkv_pk, bqkv + (size_t)L * 2304,
                                                 qkv_bf, N_REAL, 2304, EMBED, 18, 17, 1);
        // dilated attention (MFMA)
        attn_kernel<<<dim3(36, 12), 256, 0, stream>>>(qkv_bf, Obr, Lbr);
        combine_kernel<<<((N_REAL * EMBED) + 255) / 256, 256, 0, stream>>>(Obr, Lbr, attn_pk);
        // O-projection -> 4 f32 partials (nx=6, ny=17, nz=4 -> 408 blocks; nk=6)
        gemm_bf16<0, 0><<<408, 256, 0, stream>>>(attn_pk, wo_pk, bo + (size_t)L * EMBED,
                                                 tmp, N_REAL, EMBED, EMBED, 6, 17, 4);
        // LN2 folds O-proj partials into h -> packed bf16
        ln_res_kernel<true><<<N_REAL, 256, 0, stream>>>(h, tmp, 4, xln_pk,
                                                        ln2w + (size_t)L * EMBED,
                                                        ln2b + (size_t)L * EMBED, N_REAL);
        gemm_bf16<1, 3><<<408, 256, 0, stream>>>(xln_pk, w1_pk, b1 + (size_t)L * MLP_DIM,
                                                 mid_pk, N_REAL, MLP_DIM, EMBED, 24, 17, 1);
        // MLP2 -> 4 f32 partials (nx=6, ny=17, nz=4 -> 408 blocks; nk=24)
        gemm_bf16<0, 0><<<408, 256, 0, stream>>>(mid_pk, w2_pk, b2 + (size_t)L * EMBED,
                                                 tmp, N_REAL, EMBED, MLP_DIM, 6, 17, 4);
    }

    // final LN on row 0 (folds last MLP2 partials) -> d_out (768 fp32)
    ln_res_kernel<false><<<1, 256, 0, stream>>>(h, tmp, 4, (float*)d_out, lnfw, lnfb, 1);
}

// Round 17
// 929.065 us; speedup vs baseline: 1.0087x; 1.0005x over previous
//
#include <hip/hip_runtime.h>
#include <math.h>

#define EMBED 768
#define HEADS 12
#define DH 64
#define DEPTH 6
#define MLP_DIM 3072
#define N_REAL 2049
#define SP 2112            // fp32 buffer row padding (33*64)
#define SPAD 2176          // bf16 activation row padding (17*128)
#define NEGV (-1e9f)

typedef __attribute__((ext_vector_type(8))) short short8;
typedef __attribute__((ext_vector_type(4))) float f32x4;

__device__ __forceinline__ unsigned short f2bf(float f) {
    union { float f; unsigned u; } x; x.f = f;
    unsigned r = x.u + 0x7FFF + ((x.u >> 16) & 1);
    return (unsigned short)(r >> 16);
}
__device__ __forceinline__ float bf2f(unsigned short s) {
    union { unsigned u; float f; } x; x.u = (unsigned)s << 16;
    return x.f;
}

// packed fragment-blob index: blobs of 16 "major" (row for A / col for B) x 32 k.
// entry (l*8+e) of blob = element (major = l&15, k = (l>>4)*8 + e).
__device__ __forceinline__ size_t pidx(int mj, int k, int nkt) {
    return (((size_t)(mj >> 4) * nkt + (k >> 5)) << 9) + (size_t)((((k >> 3) & 3) * 16 + (mj & 15)) * 8 + (k & 7));
}

// ---------------- im2col: x -> packed patch blobs (A-layout, nkt=32) ----------------
__global__ void im2col_kernel(const float* __restrict__ x, unsigned short* __restrict__ p) {
    const int pi = blockIdx.x;            // 0..2047
    const int d = pi >> 8, rr = (pi >> 4) & 15, cc = pi & 15;
    const int t = threadIdx.x;            // 256
    #pragma unroll
    for (int u = 0; u < 4; ++u) {
        int i = u * 256 + t;              // 0..1023
        int kd = i >> 8, kr = (i >> 4) & 15, kc = i & 15;
        float v = x[(size_t)(d * 4 + kd) * 65536 + (rr * 16 + kr) * 256 + (cc * 16 + kc)];
        p[pidx(pi, i, 32)] = f2bf(v);
    }
}

// ---------------- weight pack: fp32 [K][N] -> fragment blobs (B-layout) ----------------
__device__ __forceinline__ void pack_KN_body(const float* __restrict__ src,
                                             unsigned short* __restrict__ dst,
                                             int N, int K, int bn, int bk) {
    __shared__ float lf[128][33];         // [n][k]
    const int t = threadIdx.x;
    {
        const int kk = t >> 3, ch = t & 7;
        const float4* s = (const float4*)(src + (size_t)(bk * 32 + kk) * N + bn * 128 + ch * 16);
        float4 v0 = s[0], v1 = s[1], v2 = s[2], v3 = s[3];
        float tmp[16];
        ((float4*)tmp)[0] = v0; ((float4*)tmp)[1] = v1; ((float4*)tmp)[2] = v2; ((float4*)tmp)[3] = v3;
        #pragma unroll
        for (int u = 0; u < 16; ++u) lf[ch * 16 + u][kk] = tmp[u];
    }
    __syncthreads();
    const int nkt = K >> 5;
    const int cg = t >> 5;                // blob 0..7
    const int l0 = (t & 31) * 2;
    unsigned short* o = dst + (((size_t)(bn * 8 + cg) * nkt + bk) << 9);
    #pragma unroll
    for (int q = 0; q < 2; ++q) {
        const int l = l0 + q;
        const int col = cg * 16 + (l & 15), kb = (l >> 4) * 8;
        unsigned short ov[8];
        #pragma unroll
        for (int e = 0; e < 8; ++e) ov[e] = f2bf(lf[col][kb + e]);
        *(short8*)(o + l * 8) = *(short8*)ov;
    }
}

// per-layer piece dispatch (r in [0,1728))
__device__ __forceinline__ void pack_piece(int r,
                                           const float* wq, const float* wk,
                                           const float* wv, const float* wo,
                                           const float* w1s, const float* w2s,
                                           unsigned short* qkv_pk, unsigned short* o_pk,
                                           unsigned short* w1_pk, unsigned short* w2_pk) {
    if (r < 576) {
        const int m = r / 144, rr = r % 144;
        const float* src = (m == 0) ? wq : (m == 1) ? wk : (m == 2) ? wv : wo;
        unsigned short* dst = (m < 3) ? qkv_pk + (size_t)m * EMBED * EMBED : o_pk;
        pack_KN_body(src, dst, EMBED, EMBED, rr % 6, rr / 6);
    } else if (r < 1152) {
        const int rr = r - 576;
        pack_KN_body(w1s, w1_pk, MLP_DIM, EMBED, rr % 24, rr / 24);
    } else {
        const int rr = r - 1152;
        pack_KN_body(w2s, w2_pk, EMBED, MLP_DIM, rr % 6, rr / 6);
    }
}

// one layer per launch (fallback path)
__global__ void pack_all_kernel(const float* __restrict__ wq, const float* __restrict__ wk,
                                const float* __restrict__ wv, const float* __restrict__ wo,
                                const float* __restrict__ w1s, const float* __restrict__ w2s,
                                unsigned short* __restrict__ qkv_pk, unsigned short* __restrict__ o_pk,
                                unsigned short* __restrict__ w1_pk, unsigned short* __restrict__ w2_pk) {
    pack_piece(blockIdx.x, wq, wk, wv, wo, w1s, w2s, qkv_pk, o_pk, w1_pk, w2_pk);
}

// all DEPTH layers in one launch (grid = DEPTH*1728)
__global__ void pack_mega_kernel(const float* __restrict__ wq, const float* __restrict__ wk,
                                 const float* __restrict__ wv, const float* __restrict__ wo,
                                 const float* __restrict__ w1s, const float* __restrict__ w2s,
                                 unsigned short* __restrict__ qkv_pk, unsigned short* __restrict__ o_pk,
                                 unsigned short* __restrict__ w1_pk, unsigned short* __restrict__ w2_pk) {
    const int lid = blockIdx.x / 1728;
    const int r = blockIdx.x % 1728;
    const size_t EE = (size_t)EMBED * EMBED, EM = (size_t)EMBED * MLP_DIM;
    pack_piece(r, wq + lid * EE, wk + lid * EE, wv + lid * EE, wo + lid * EE,
               w1s + lid * EM, w2s + lid * EM,
               qkv_pk + (size_t)lid * 3 * EE, o_pk + lid * EE,
               w1_pk + lid * EM, w2_pk + lid * EM);
}

// pack from fp32 [N][K] (conv_w: [768][1024])
__global__ void pack_NK_kernel(const float* __restrict__ src, unsigned short* __restrict__ dst,
                               int N, int K) {
    __shared__ float lf[128][33];
    const int bn = blockIdx.x, bk = blockIdx.y;
    const int t = threadIdx.x;
    {
        const int row = t >> 1, hf = t & 1;
        const float4* s = (const float4*)(src + (size_t)(bn * 128 + row) * K + bk * 32 + hf * 16);
        float4 v0 = s[0], v1 = s[1], v2 = s[2], v3 = s[3];
        float tmp[16];
        ((float4*)tmp)[0] = v0; ((float4*)tmp)[1] = v1; ((float4*)tmp)[2] = v2; ((float4*)tmp)[3] = v3;
        #pragma unroll
        for (int u = 0; u < 16; ++u) lf[row][hf * 16 + u] = tmp[u];
    }
    __syncthreads();
    const int nkt = K >> 5;
    const int cg = t >> 5;
    const int l0 = (t & 31) * 2;
    unsigned short* o = dst + (((size_t)(bn * 8 + cg) * nkt + bk) << 9);
    #pragma unroll
    for (int q = 0; q < 2; ++q) {
        const int l = l0 + q;
        const int col = cg * 16 + (l & 15), kb = (l >> 4) * 8;
        unsigned short ov[8];
        #pragma unroll
        for (int e = 0; e < 8; ++e) ov[e] = f2bf(lf[col][kb + e]);
        *(short8*)(o + l * 8) = *(short8*)ov;
    }
}

// ---------------- misc init: qkv bias concat (all layers) + cls token row ----------------
__global__ void init_misc_kernel(const float* __restrict__ bq, const float* __restrict__ bk,
                                 const float* __restrict__ bv, float* __restrict__ bqkv,
                                 const float* __restrict__ cls, const float* __restrict__ pos,
                                 float* __restrict__ h) {
    int i = blockIdx.x * 256 + threadIdx.x;
    if (i < DEPTH * 2304) {
        int L = i / 2304, j = i - L * 2304;
        float v = (j < 768) ? bq[L * 768 + j] : (j < 1536) ? bk[L * 768 + j - 768] : bv[L * 768 + j - 1536];
        bqkv[i] = v;
    }
    int j = i - DEPTH * 2304;
    if (j >= 0 && j < EMBED) h[j] = cls[j] + pos[j];
}

// h[1+pi] = pos[1+pi] + sum_{c<4} tmp[c][pi]  (patch-embed partial merge)
__global__ void embed_add_kernel(const float* __restrict__ pos, const float* __restrict__ tmp,
                                 float* __restrict__ h) {
    int gid = blockIdx.x * 256 + threadIdx.x;
    if (gid >= 2048 * EMBED) return;
    float v = pos[EMBED + gid];
    #pragma unroll
    for (int c = 0; c < 4; ++c) v += tmp[(size_t)c * SP * EMBED + gid];
    h[EMBED + gid] = v;
}

// ---------------- layernorm (plain): one block per row; packed-bf16 (nkt=24) out ----------------
template<bool PACKED>
__global__ void ln_kernel(const float* __restrict__ in, void* __restrict__ outv,
                          const float* __restrict__ w, const float* __restrict__ b,
                          int M) {
    int row = blockIdx.x;
    if (row >= M) return;
    const float* xr = in + (size_t)row * EMBED;
    int tid = threadIdx.x;
    float v0 = xr[tid], v1 = xr[tid + 256], v2 = xr[tid + 512];
    __shared__ float red[4];
    float s = v0 + v1 + v2;
    #pragma unroll
    for (int o = 32; o > 0; o >>= 1) s += __shfl_down(s, o);
    if ((tid & 63) == 0) red[tid >> 6] = s;
    __syncthreads();
    float mean = (red[0] + red[1] + red[2] + red[3]) * (1.0f / 768.0f);
    __syncthreads();
    float d0 = v0 - mean, d1 = v1 - mean, d2 = v2 - mean;
    float q2 = d0 * d0 + d1 * d1 + d2 * d2;
    #pragma unroll
    for (int o = 32; o > 0; o >>= 1) q2 += __shfl_down(q2, o);
    if ((tid & 63) == 0) red[tid >> 6] = q2;
    __syncthreads();
    float var = (red[0] + red[1] + red[2] + red[3]) * (1.0f / 768.0f);
    float rstd = 1.0f / sqrtf(var + 1e-5f);
    float o0 = d0 * rstd * w[tid]       + b[tid];
    float o1 = d1 * rstd * w[tid + 256] + b[tid + 256];
    float o2 = d2 * rstd * w[tid + 512] + b[tid + 512];
    if (PACKED) {
        unsigned short* o = (unsigned short*)outv;
        o[pidx(row, tid,       24)] = f2bf(o0);
        o[pidx(row, tid + 256, 24)] = f2bf(o1);
        o[pidx(row, tid + 512, 24)] = f2bf(o2);
    } else {
        float* orow = (float*)outv + (size_t)row * EMBED;
        orow[tid] = o0; orow[tid + 256] = o1; orow[tid + 512] = o2;
    }
}

// ---------------- layernorm + fused residual: v = h + sum_{c<nt} tmp[c]; h = v; LN(v) ----------
template<bool PACKED>
__global__ void ln_res_kernel(float* __restrict__ h, const float* __restrict__ tmp, int nt,
                              void* __restrict__ outv,
                              const float* __restrict__ w, const float* __restrict__ b,
                              int M) {
    int row = blockIdx.x;
    if (row >= M) return;
    const size_t base = (size_t)row * EMBED;
    int tid = threadIdx.x;
    float v0 = h[base + tid], v1 = h[base + tid + 256], v2 = h[base + tid + 512];
    for (int c = 0; c < nt; ++c) {
        const float* tc = tmp + (size_t)c * SP * EMBED + base;
        v0 += tc[tid]; v1 += tc[tid + 256]; v2 += tc[tid + 512];
    }
    h[base + tid] = v0; h[base + tid + 256] = v1; h[base + tid + 512] = v2;
    __shared__ float red[4];
    float s = v0 + v1 + v2;
    #pragma unroll
    for (int o = 32; o > 0; o >>= 1) s += __shfl_down(s, o);
    if ((tid & 63) == 0) red[tid >> 6] = s;
    __syncthreads();
    float mean = (red[0] + red[1] + red[2] + red[3]) * (1.0f / 768.0f);
    __syncthreads();
    float d0 = v0 - mean, d1 = v1 - mean, d2 = v2 - mean;
    float q2 = d0 * d0 + d1 * d1 + d2 * d2;
    #pragma unroll
    for (int o = 32; o > 0; o >>= 1) q2 += __shfl_down(q2, o);
    if ((tid & 63) == 0) red[tid >> 6] = q2;
    __syncthreads();
    float var = (red[0] + red[1] + red[2] + red[3]) * (1.0f / 768.0f);
    float rstd = 1.0f / sqrtf(var + 1e-5f);
    float o0 = d0 * rstd * w[tid]       + b[tid];
    float o1 = d1 * rstd * w[tid + 256] + b[tid + 256];
    float o2 = d2 * rstd * w[tid + 512] + b[tid + 512];
    if (PACKED) {
        unsigned short* o = (unsigned short*)outv;
        o[pidx(row, tid,       24)] = f2bf(o0);
        o[pidx(row, tid + 256, 24)] = f2bf(o1);
        o[pidx(row, tid + 512, 24)] = f2bf(o2);
    } else {
        float* orow = (float*)outv + (size_t)row * EMBED;
        orow[tid] = o0; orow[tid + 256] = o1; orow[tid + 512] = o2;
    }
}

// ---------------- bf16 MFMA GEMM: LDS-free, fragment-packed, 128x128 block (2x2 waves) ----
// 1D grid with bijective XCD swizzle (m204), x-fastest work order for A-panel L2 locality.
// MODE 0: f32 partial store, chunk bz writes Cf + bz*SP*EMBED (N must be 768; bias chunk 0).
// MODE 2: bf16 row-major store. MODE 3: bf16 packed store. MODE 2/3 require nz == 1.
// No atomics (round-12/15: atomic-unit throughput was binding the accum GEMMs).
template<int ACT, int MODE>
__global__ __launch_bounds__(256)
void gemm_bf16(const unsigned short* __restrict__ Apk, const unsigned short* __restrict__ Bpk,
               const float* __restrict__ bias, void* __restrict__ Cv,
               int M, int N, int K, int nx, int ny, int nz) {
    // --- bijective XCD swizzle ---
    const int nwg = nx * ny * nz;
    const int fid = blockIdx.x;
    const int xcd = fid & 7, slot = fid >> 3;
    const int qq = nwg >> 3, rr2 = nwg & 7;
    const int orig = (xcd < rr2 ? xcd * (qq + 1) : rr2 * (qq + 1) + (xcd - rr2) * qq) + slot;
    const int bx = orig % nx;
    const int tzy = orig / nx;
    const int bz = tzy % nz;
    const int by = tzy / nz;

    const int tid = threadIdx.x;
    const int lane = tid & 63;
    const int w4 = tid >> 6;
    const int wm = w4 >> 1, wn = w4 & 1;
    const int row0 = by * 128 + wm * 64, col0 = bx * 128 + wn * 64;
    const int nktT = K >> 5;                       // total K tiles
    const int nk = nktT / nz;                      // tiles this chunk
    const int t0 = bz * nk;

    f32x4 acc[4][4];
    #pragma unroll
    for (int mi = 0; mi < 4; ++mi)
        #pragma unroll
        for (int ni = 0; ni < 4; ++ni)
            #pragma unroll
            for (int j = 0; j < 4; ++j) acc[mi][ni][j] = 0.0f;

    const unsigned short* Ab[4];
    const unsigned short* Bb[4];
    #pragma unroll
    for (int i = 0; i < 4; ++i) {
        Ab[i] = Apk + (((size_t)(by * 8 + wm * 4 + i) * nktT + t0) << 9) + lane * 8;
        Bb[i] = Bpk + (((size_t)(bx * 8 + wn * 4 + i) * nktT + t0) << 9) + lane * 8;
    }

    auto LOADT = [&](int t, short8* aa, short8* bb) {
        #pragma unroll
        for (int i = 0; i < 4; ++i) {
            aa[i] = *(const short8*)(Ab[i] + (size_t)t * 512);
            bb[i] = *(const short8*)(Bb[i] + (size_t)t * 512);
        }
    };
    auto MF = [&](short8* aa, short8* bb) {
        #pragma unroll
        for (int mi = 0; mi < 4; ++mi)
            #pragma unroll
            for (int ni = 0; ni < 4; ++ni)
                acc[mi][ni] = __builtin_amdgcn_mfma_f32_16x16x32_bf16(aa[mi], bb[ni], acc[mi][ni], 0, 0, 0);
    };

    short8 A0[4], B0[4], A1[4], B1[4];
    LOADT(0, A0, B0);
    for (int t = 0; t < nk; t += 2) {              // nk % 2 == 0
        LOADT(t + 1, A1, B1);
        MF(A0, B0);
        if (t + 2 < nk) LOADT(t + 2, A0, B0);
        MF(A1, B1);
    }

    float* Cf = (float*)Cv + (MODE == 0 ? (size_t)bz * SP * EMBED : 0);
    unsigned short* Cb = (unsigned short*)Cv;
    const int ln15 = lane & 15, kq = lane >> 4;
    const int nktN = N >> 5;
    const bool addb = (bz == 0);
    #pragma unroll
    for (int mi = 0; mi < 4; ++mi) {
        #pragma unroll
        for (int ni = 0; ni < 4; ++ni) {
            const int col = col0 + ni * 16 + ln15;
            const float bb = addb ? bias[col] : 0.0f;
            #pragma unroll
            for (int j = 0; j < 4; ++j) {
                const int row = row0 + mi * 16 + kq * 4 + j;
                if (row < M) {
                    float v = acc[mi][ni][j] + bb;
                    if (ACT == 1) v = 0.5f * v * (1.0f + erff(v * 0.70710678118654752f));
                    if (MODE == 0)      Cf[(size_t)row * N + col] = v;
                    else if (MODE == 2) Cb[(size_t)row * N + col] = f2bf(v);
                    else                Cb[pidx(row, col, nktN)] = f2bf(v);
                }
            }
        }
    }
}

// ---------------- dilated attention: MFMA (bf16 qkv in, bf16 Obr out) ----------------
__global__ __launch_bounds__(256, 1)
void attn_kernel(const unsigned short* __restrict__ qkv,
                 unsigned short* __restrict__ Obr, float* __restrict__ Lbr) {
    const int bx = blockIdx.x, hh = blockIdx.y;
    int b, n;
    if      (bx < 17) { b = 0; n = bx; }
    else if (bx < 26) { b = 1; n = bx - 17; }
    else if (bx < 31) { b = 2; n = bx - 26; }
    else if (bx < 34) { b = 3; n = bx - 31; }
    else              { b = 4; n = bx - 34; }
    const int r = 1 << b;
    const int segw = 128 << b;
    const int base = n * segw + (hh & (r - 1));

    __shared__ __attribute__((aligned(16))) unsigned short VT[64 * 128];   // [d][k] swizzled
    __shared__ __attribute__((aligned(16))) unsigned short Pl[128 * 128];  // [q][k] swizzled

    const int tid = threadIdx.x;

    // ---- stage V^T (transposed + swizzled) ----
    {
        const int key = tid >> 1, dh2 = (tid & 1) * 32;
        const int pos = base + r * key;
        const bool val = pos < N_REAL;
        const unsigned short* vsrc = qkv + (size_t)(val ? pos : 0) * 2304 + 1536 + hh * 64 + dh2;
        #pragma unroll
        for (int u = 0; u < 4; ++u) {
            short8 vv = ((const short8*)vsrc)[u];
            #pragma unroll
            for (int e = 0; e < 8; ++e) {
                const int d = dh2 + u * 8 + e;
                VT[(d * 256 + ((key * 2) ^ ((d & 7) << 4))) >> 1] =
                    val ? (unsigned short)vv[e] : (unsigned short)0;
            }
        }
    }
    __syncthreads();

    const int lane = tid & 63, wv = tid >> 6;
    const int ln15 = lane & 15, kq = lane >> 4;

    // ---- QK^T ----
    f32x4 sc[2][8];
    #pragma unroll
    for (int mi = 0; mi < 2; ++mi)
        #pragma unroll
        for (int ni = 0; ni < 8; ++ni)
            #pragma unroll
            for (int j = 0; j < 4; ++j) sc[mi][ni][j] = 0.0f;

    #pragma unroll
    for (int kt = 0; kt < 2; ++kt) {
        short8 qfr[2], kfr[8];
        #pragma unroll
        for (int mi = 0; mi < 2; ++mi) {
            const int pos = base + r * (wv * 32 + mi * 16 + ln15);
            qfr[mi] = *(const short8*)(qkv + (size_t)(pos < N_REAL ? pos : 0) * 2304
                                       + hh * 64 + kt * 32 + kq * 8);
        }
        #pragma unroll
        for (int ni = 0; ni < 8; ++ni) {
            const int pos = base + r * (ni * 16 + ln15);
            kfr[ni] = *(const short8*)(qkv + (size_t)(pos < N_REAL ? pos : 0) * 2304
                                       + 768 + hh * 64 + kt * 32 + kq * 8);
        }
        #pragma unroll
        for (int mi = 0; mi < 2; ++mi)
            #pragma unroll
            for (int ni = 0; ni < 8; ++ni)
                sc[mi][ni] = __builtin_amdgcn_mfma_f32_16x16x32_bf16(qfr[mi], kfr[ni], sc[mi][ni], 0, 0, 0);
    }

    // scale + key mask
    #pragma unroll
    for (int ni = 0; ni < 8; ++ni) {
        const bool kval = (base + r * (ni * 16 + ln15)) < N_REAL;
        #pragma unroll
        for (int mi = 0; mi < 2; ++mi)
            #pragma unroll
            for (int j = 0; j < 4; ++j)
                sc[mi][ni][j] = kval ? sc[mi][ni][j] * 0.125f : NEGV;
    }

    // ---- wave-local row softmax ----
    float rsum[2][4];
    #pragma unroll
    for (int mi = 0; mi < 2; ++mi) {
        #pragma unroll
        for (int j = 0; j < 4; ++j) {
            float mx = sc[mi][0][j];
            #pragma unroll
            for (int ni = 1; ni < 8; ++ni) mx = fmaxf(mx, sc[mi][ni][j]);
            mx = fmaxf(mx, __shfl_xor(mx, 1));
            mx = fmaxf(mx, __shfl_xor(mx, 2));
            mx = fmaxf(mx, __shfl_xor(mx, 4));
            mx = fmaxf(mx, __shfl_xor(mx, 8));
            float sm = 0.f;
            #pragma unroll
            for (int ni = 0; ni < 8; ++ni) {
                float e = __expf(sc[mi][ni][j] - mx);
                sc[mi][ni][j] = e;
                sm += e;
            }
            sm += __shfl_xor(sm, 1);
            sm += __shfl_xor(sm, 2);
            sm += __shfl_xor(sm, 4);
            sm += __shfl_xor(sm, 8);
            rsum[mi][j] = sm;
            const int prow = wv * 32 + mi * 16 + kq * 4 + j;
            const int qpos = base + r * prow;
            if (ln15 == 0 && qpos < N_REAL)
                Lbr[((size_t)b * SP + qpos) * HEADS + hh] = mx + logf(sm);
        }
    }

    // ---- write P to LDS (bf16, swizzled) ----
    #pragma unroll
    for (int mi = 0; mi < 2; ++mi)
        #pragma unroll
        for (int j = 0; j < 4; ++j) {
            const int prow = wv * 32 + mi * 16 + kq * 4 + j;
            #pragma unroll
            for (int ni = 0; ni < 8; ++ni) {
                const int col = ni * 16 + ln15;
                Pl[(prow * 256 + ((col * 2) ^ ((prow & 7) << 4))) >> 1] = f2bf(sc[mi][ni][j]);
            }
        }
    __syncthreads();

    // ---- PV: O[32 q][64 d] per wave, K=128 ----
    f32x4 ov[2][4];
    #pragma unroll
    for (int mi = 0; mi < 2; ++mi)
        #pragma unroll
        for (int ni = 0; ni < 4; ++ni)
            #pragma unroll
            for (int j = 0; j < 4; ++j) ov[mi][ni][j] = 0.0f;

    #pragma unroll
    for (int kt = 0; kt < 4; ++kt) {
        short8 pa[2], vb[4];
        #pragma unroll
        for (int mi = 0; mi < 2; ++mi) {
            const int row = wv * 32 + mi * 16 + ln15;
            pa[mi] = *(const short8*)((const char*)Pl + row * 256
                                      + ((kt * 64 + kq * 16) ^ ((row & 7) << 4)));
        }
        #pragma unroll
        for (int ni = 0; ni < 4; ++ni) {
            const int d = ni * 16 + ln15;
            vb[ni] = *(const short8*)((const char*)VT + d * 256
                                      + ((kt * 64 + kq * 16) ^ ((d & 7) << 4)));
        }
        #pragma unroll
        for (int mi = 0; mi < 2; ++mi)
            #pragma unroll
            for (int ni = 0; ni < 4; ++ni)
                ov[mi][ni] = __builtin_amdgcn_mfma_f32_16x16x32_bf16(pa[mi], vb[ni], ov[mi][ni], 0, 0, 0);
    }

    // ---- epilogue: normalize + store ----
    #pragma unroll
    for (int mi = 0; mi < 2; ++mi)
        #pragma unroll
        for (int j = 0; j < 4; ++j) {
            const int prow = wv * 32 + mi * 16 + kq * 4 + j;
            const int qpos = base + r * prow;
            if (qpos < N_REAL) {
                const float inv = 1.0f / rsum[mi][j];
                #pragma unroll
                for (int ni = 0; ni < 4; ++ni)
                    Obr[((size_t)b * N_REAL + qpos) * EMBED + hh * 64 + ni * 16 + ln15] =
                        f2bf(ov[mi][ni][j] * inv);
            }
        }
}

// ---------------- branch combine -> packed bf16 (A-layout, nkt=24) ----------------
__global__ void combine_kernel(const unsigned short* __restrict__ Obr, const float* __restrict__ Lbr,
                               unsigned short* __restrict__ out) {
    int gid = blockIdx.x * 256 + threadIdx.x;
    if (gid >= N_REAL * EMBED) return;
    int p = gid / EMBED, e = gid - p * EMBED;
    int h = e >> 6;
    float l[5];
    float mx = NEGV;
    #pragma unroll
    for (int b = 0; b < 5; ++b) {
        const int rm = (1 << b) - 1;
        l[b] = ((p & rm) == (h & rm)) ? Lbr[((size_t)b * SP + p) * HEADS + h] : NEGV;
        mx = fmaxf(mx, l[b]);
    }
    float wsum = 0.f, acc = 0.f;
    #pragma unroll
    for (int b = 0; b < 5; ++b) {
        if (l[b] > NEGV * 0.5f) {
            float wt = expf(l[b] - mx);
            wsum += wt;
            acc += wt * bf2f(Obr[((size_t)b * N_REAL + p) * EMBED + e]);
        }
    }
    out[pidx(p, e, 24)] = f2bf(acc / wsum);
}

// ---------------- host orchestration ----------------
extern "C" void kernel_launch(void* const* d_in, const int* in_sizes, int n_in,
                              void* d_out, int out_size, void* d_ws, size_t ws_size,
                              hipStream_t stream) {
    const float* x      = (const float*)d_in[0];
    const float* conv_w = (const float*)d_in[1];
    const float* conv_b = (const float*)d_in[2];
    const float* cls    = (const float*)d_in[3];
    const float* pos    = (const float*)d_in[4];
    const float* ln1w   = (const float*)d_in[5];
    const float* ln1b   = (const float*)d_in[6];
    const float* wq     = (const float*)d_in[7];
    const float* bq     = (const float*)d_in[8];
    const float* wk     = (const float*)d_in[9];
    const float* bk     = (const float*)d_in[10];
    const float* wv     = (const float*)d_in[11];
    const float* bv     = (const float*)d_in[12];
    const float* wo     = (const float*)d_in[13];
    const float* bo     = (const float*)d_in[14];
    const float* ln2w   = (const float*)d_in[15];
    const float* ln2b   = (const float*)d_in[16];
    const float* w1     = (const float*)d_in[17];
    const float* b1     = (const float*)d_in[18];
    const float* w2     = (const float*)d_in[19];
    const float* b2     = (const float*)d_in[20];
    const float* lnfw   = (const float*)d_in[21];
    const float* lnfb   = (const float*)d_in[22];

    const size_t EE = (size_t)EMBED * EMBED;
    const size_t EM = (size_t)EMBED * MLP_DIM;

    // decide upfront vs per-layer weight packing based on ws_size (host-side, deterministic)
    const size_t base_floats =
        (size_t)SP * EMBED                      // h
        + 4 * (size_t)SP * EMBED                // tmp
        + 5 * (size_t)SP * HEADS                // Lbr
        + (size_t)DEPTH * 2304                  // bqkv
        + (size_t)SPAD * 2304 / 2               // qkv_bf
        + (size_t)SPAD * EMBED / 2              // xln_pk
        + (size_t)SPAD * EMBED / 2              // attn_pk
        + (size_t)SPAD * MLP_DIM / 2            // mid_pk
        + (size_t)2112 * 1024 / 2               // patch_pk
        + (size_t)EMBED * 1024 / 2              // convw_pk
        + ((size_t)5 * N_REAL * EMBED / 2 + 64);// Obr
    const size_t per_layer_floats = (3 * EE + EE + EM + EM) / 2;
    const bool up = ws_size >= (base_floats + 6 * per_layer_floats) * 4 + (1 << 20);
    const int NL = up ? DEPTH : 1;

    float* ws = (float*)d_ws;
    float* h     = ws;  ws += (size_t)SP * EMBED;
    float* tmp   = ws;  ws += (size_t)4 * SP * EMBED;
    float* Lbr   = ws;  ws += (size_t)5 * SP * HEADS;
    float* bqkv  = ws;  ws += (size_t)DEPTH * 2304;
    unsigned short* qkv_bf   = (unsigned short*)ws;  ws += (size_t)SPAD * 2304 / 2;
    unsigned short* xln_pk   = (unsigned short*)ws;  ws += (size_t)SPAD * EMBED / 2;
    unsigned short* attn_pk  = (unsigned short*)ws;  ws += (size_t)SPAD * EMBED / 2;
    unsigned short* mid_pk   = (unsigned short*)ws;  ws += (size_t)SPAD * MLP_DIM / 2;
    unsigned short* patch_pk = (unsigned short*)ws;  ws += (size_t)2112 * 1024 / 2;
    unsigned short* convw_pk = (unsigned short*)ws;  ws += (size_t)EMBED * 1024 / 2;
    unsigned short* Obr      = (unsigned short*)ws;  ws += (size_t)5 * N_REAL * EMBED / 2 + 64;
    unsigned short* wqkv_pk  = (unsigned short*)ws;  ws += (size_t)NL * 3 * EE / 2;
    unsigned short* wo_pk    = (unsigned short*)ws;  ws += (size_t)NL * EE / 2;
    unsigned short* w1_pk    = (unsigned short*)ws;  ws += (size_t)NL * EM / 2;
    unsigned short* w2_pk    = (unsigned short*)ws;  ws += (size_t)NL * EM / 2;

    // ---- upfront packing / init ----
    im2col_kernel<<<2048, 256, 0, stream>>>(x, patch_pk);
    pack_NK_kernel<<<dim3(6, 32), 256, 0, stream>>>(conv_w, convw_pk, EMBED, 1024);
    init_misc_kernel<<<(DEPTH * 2304 + EMBED + 255) / 256, 256, 0, stream>>>(
        bq, bk, bv, bqkv, cls, pos, h);
    if (up)
        pack_mega_kernel<<<DEPTH * 1728, 256, 0, stream>>>(wq, wk, wv, wo, w1, w2,
                                                           wqkv_pk, wo_pk, w1_pk, w2_pk);
    // patch GEMM -> 4 f32 partials, then merge with pos
    gemm_bf16<0, 0><<<384, 256, 0, stream>>>(patch_pk, convw_pk, conv_b,
                                             tmp, 2048, EMBED, 1024, 6, 16, 4);
    embed_add_kernel<<<(2048 * EMBED + 255) / 256, 256, 0, stream>>>(pos, tmp, h);

    for (int L = 0; L < DEPTH; ++L) {
        const int off = up ? L : 0;
        unsigned short* qkvW = wqkv_pk + (size_t)off * 3 * EE;
        unsigned short* woW  = wo_pk   + (size_t)off * EE;
        unsigned short* w1W  = w1_pk   + (size_t)off * EM;
        unsigned short* w2W  = w2_pk   + (size_t)off * EM;
        if (!up)
            pack_all_kernel<<<1728, 256, 0, stream>>>(wq + L * EE, wk + L * EE, wv + L * EE,
                                                      wo + L * EE, w1 + L * EM, w2 + L * EM,
                                                      qkvW, woW, w1W, w2W);

        // LN1 -> packed bf16 (layer 0: h final; layers 1..5: fold prev MLP2's 4 partials)
        if (L == 0)
            ln_kernel<true><<<N_REAL, 256, 0, stream>>>(h, xln_pk, ln1w + (size_t)L * EMBED,
                                                        ln1b + (size_t)L * EMBED, N_REAL);
        else
            ln_res_kernel<true><<<N_REAL, 256, 0, stream>>>(h, tmp, 4, xln_pk,
                                                            ln1w + (size_t)L * EMBED,
                                                            ln1b + (size_t)L * EMBED, N_REAL);
        // fused QKV -> row-major bf16
        gemm_bf16<0, 2><<<306, 256, 0, stream>>>(xln_pk, qkvW, bqkv + (size_t)L * 2304,
                                                 qkv_bf, N_REAL, 2304, EMBED, 18, 17, 1);
        // dilated attention (MFMA)
        attn_kernel<<<dim3(36, 12), 256, 0, stream>>>(qkv_bf, Obr, Lbr);
        combine_kernel<<<((N_REAL * EMBED) + 255) / 256, 256, 0, stream>>>(Obr, Lbr, attn_pk);
        // O-projection -> 4 f32 partials
        gemm_bf16<0, 0><<<408, 256, 0, stream>>>(attn_pk, woW, bo + (size_t)L * EMBED,
                                                 tmp, N_REAL, EMBED, EMBED, 6, 17, 4);
        // LN2 folds O-proj partials into h -> packed bf16
        ln_res_kernel<true><<<N_REAL, 256, 0, stream>>>(h, tmp, 4, xln_pk,
                                                        ln2w + (size_t)L * EMBED,
                                                        ln2b + (size_t)L * EMBED, N_REAL);
        gemm_bf16<1, 3><<<408, 256, 0, stream>>>(xln_pk, w1W, b1 + (size_t)L * MLP_DIM,
                                                 mid_pk, N_REAL, MLP_DIM, EMBED, 24, 17, 1);
        // MLP2 -> 4 f32 partials (folded by next LN1 / final LN)
        gemm_bf16<0, 0><<<408, 256, 0, stream>>>(mid_pk, w2W, b2 + (size_t)L * EMBED,
                                                 tmp, N_REAL, EMBED, MLP_DIM, 6, 17, 4);
    }

    // final LN on row 0 (folds last MLP2 partials) -> d_out (768 fp32)
    ln_res_kernel<false><<<1, 256, 0, stream>>>(h, tmp, 4, (float*)d_out, lnfw, lnfb, 1);
}

// Round 18
// 909.647 us; speedup vs baseline: 1.0302x; 1.0213x over previous
//
#include <hip/hip_runtime.h>
#include <math.h>

#define EMBED 768
#define HEADS 12
#define DH 64
#define DEPTH 6
#define MLP_DIM 3072
#define N_REAL 2049
#define SP 2112            // fp32 buffer row padding (33*64)
#define SPAD 2176          // bf16 activation row padding (17*128)
#define NEGV (-1e9f)

typedef __attribute__((ext_vector_type(8))) short short8;
typedef __attribute__((ext_vector_type(4))) float f32x4;

__device__ __forceinline__ unsigned short f2bf(float f) {
    union { float f; unsigned u; } x; x.f = f;
    unsigned r = x.u + 0x7FFF + ((x.u >> 16) & 1);
    return (unsigned short)(r >> 16);
}
__device__ __forceinline__ float bf2f(unsigned short s) {
    union { unsigned u; float f; } x; x.u = (unsigned)s << 16;
    return x.f;
}

// fast exact-GELU: erf via Abramowitz-Stegun 7.1.26 (|err| <= 1.5e-7) + __expf
__device__ __forceinline__ float fast_gelu(float v) {
    const float ax = fabsf(v) * 0.70710678118654752f;
    const float tt = 1.0f / (1.0f + 0.3275911f * ax);
    const float poly = tt * (0.254829592f + tt * (-0.284496736f + tt * (1.421413741f
                       + tt * (-1.453152027f + tt * 1.061405429f))));
    float er = 1.0f - poly * __expf(-ax * ax);
    er = (v < 0.0f) ? -er : er;
    return 0.5f * v * (1.0f + er);
}

// packed fragment-blob index: blobs of 16 "major" (row for A / col for B) x 32 k.
// entry (l*8+e) of blob = element (major = l&15, k = (l>>4)*8 + e).
__device__ __forceinline__ size_t pidx(int mj, int k, int nkt) {
    return (((size_t)(mj >> 4) * nkt + (k >> 5)) << 9) + (size_t)((((k >> 3) & 3) * 16 + (mj & 15)) * 8 + (k & 7));
}

// ---------------- im2col body: one patch row -> packed blobs (A-layout, nkt=32) ------------
__device__ __forceinline__ void im2col_body(const float* __restrict__ x,
                                            unsigned short* __restrict__ p, int pi) {
    const int d = pi >> 8, rr = (pi >> 4) & 15, cc = pi & 15;
    const int t = threadIdx.x;            // 256
    #pragma unroll
    for (int u = 0; u < 4; ++u) {
        int i = u * 256 + t;              // 0..1023
        int kd = i >> 8, kr = (i >> 4) & 15, kc = i & 15;
        float v = x[(size_t)(d * 4 + kd) * 65536 + (rr * 16 + kr) * 256 + (cc * 16 + kc)];
        p[pidx(pi, i, 32)] = f2bf(v);
    }
}

__global__ void im2col_kernel(const float* __restrict__ x, unsigned short* __restrict__ p) {
    im2col_body(x, p, blockIdx.x);
}

// ---------------- weight pack: fp32 [K][N] -> fragment blobs (B-layout) ----------------
// LDS layout: row r (=output col), k-index kk stored at column (kk + 4*(r>>4)) & 31.
// Write bank = (20*ch + u + kk) % 32 -> exactly 2 lanes/bank (free). Reader inverts rotation.
__device__ __forceinline__ void pack_KN_body(const float* __restrict__ src,
                                             unsigned short* __restrict__ dst,
                                             int N, int K, int bn, int bk) {
    __shared__ float lf[128][33];         // [n][k-rotated]
    const int t = threadIdx.x;
    {
        const int kk = t >> 3, ch = t & 7;
        const float4* s = (const float4*)(src + (size_t)(bk * 32 + kk) * N + bn * 128 + ch * 16);
        float4 v0 = s[0], v1 = s[1], v2 = s[2], v3 = s[3];
        float tmp[16];
        ((float4*)tmp)[0] = v0; ((float4*)tmp)[1] = v1; ((float4*)tmp)[2] = v2; ((float4*)tmp)[3] = v3;
        const int cidx = (kk + 4 * ch) & 31;
        #pragma unroll
        for (int u = 0; u < 16; ++u) lf[ch * 16 + u][cidx] = tmp[u];
    }
    __syncthreads();
    const int nkt = K >> 5;
    const int cg = t >> 5;                // blob 0..7
    const int l0 = (t & 31) * 2;
    const int rot = 4 * cg;               // col>>4 == cg for this thread's cols
    unsigned short* o = dst + (((size_t)(bn * 8 + cg) * nkt + bk) << 9);
    #pragma unroll
    for (int q = 0; q < 2; ++q) {
        const int l = l0 + q;
        const int col = cg * 16 + (l & 15), kb = (l >> 4) * 8;
        unsigned short ov[8];
        #pragma unroll
        for (int e = 0; e < 8; ++e) ov[e] = f2bf(lf[col][(kb + e + rot) & 31]);
        *(short8*)(o + l * 8) = *(short8*)ov;
    }
}

// per-layer piece dispatch (r in [0,1728))
__device__ __forceinline__ void pack_piece(int r,
                                           const float* wq, const float* wk,
                                           const float* wv, const float* wo,
                                           const float* w1s, const float* w2s,
                                           unsigned short* qkv_pk, unsigned short* o_pk,
                                           unsigned short* w1_pk, unsigned short* w2_pk) {
    if (r < 576) {
        const int m = r / 144, rr = r % 144;
        const float* src = (m == 0) ? wq : (m == 1) ? wk : (m == 2) ? wv : wo;
        unsigned short* dst = (m < 3) ? qkv_pk + (size_t)m * EMBED * EMBED : o_pk;
        pack_KN_body(src, dst, EMBED, EMBED, rr % 6, rr / 6);
    } else if (r < 1152) {
        const int rr = r - 576;
        pack_KN_body(w1s, w1_pk, MLP_DIM, EMBED, rr % 24, rr / 24);
    } else {
        const int rr = r - 1152;
        pack_KN_body(w2s, w2_pk, EMBED, MLP_DIM, rr % 6, rr / 6);
    }
}

// one layer per launch (fallback path)
__global__ void pack_all_kernel(const float* __restrict__ wq, const float* __restrict__ wk,
                                const float* __restrict__ wv, const float* __restrict__ wo,
                                const float* __restrict__ w1s, const float* __restrict__ w2s,
                                unsigned short* __restrict__ qkv_pk, unsigned short* __restrict__ o_pk,
                                unsigned short* __restrict__ w1_pk, unsigned short* __restrict__ w2_pk) {
    pack_piece(blockIdx.x, wq, wk, wv, wo, w1s, w2s, qkv_pk, o_pk, w1_pk, w2_pk);
}

// pack from fp32 [N][K] body (conv_w: [768][1024]); write bank already 2-way (free)
__device__ __forceinline__ void pack_NK_body(const float* __restrict__ src,
                                             unsigned short* __restrict__ dst,
                                             int N, int K, int bn, int bk) {
    __shared__ float lf[128][33];
    const int t = threadIdx.x;
    {
        const int row = t >> 1, hf = t & 1;
        const float4* s = (const float4*)(src + (size_t)(bn * 128 + row) * K + bk * 32 + hf * 16);
        float4 v0 = s[0], v1 = s[1], v2 = s[2], v3 = s[3];
        float tmp[16];
        ((float4*)tmp)[0] = v0; ((float4*)tmp)[1] = v1; ((float4*)tmp)[2] = v2; ((float4*)tmp)[3] = v3;
        #pragma unroll
        for (int u = 0; u < 16; ++u) lf[row][hf * 16 + u] = tmp[u];
    }
    __syncthreads();
    const int nkt = K >> 5;
    const int cg = t >> 5;
    const int l0 = (t & 31) * 2;
    unsigned short* o = dst + (((size_t)(bn * 8 + cg) * nkt + bk) << 9);
    #pragma unroll
    for (int q = 0; q < 2; ++q) {
        const int l = l0 + q;
        const int col = cg * 16 + (l & 15), kb = (l >> 4) * 8;
        unsigned short ov[8];
        #pragma unroll
        for (int e = 0; e < 8; ++e) ov[e] = f2bf(lf[col][kb + e]);
        *(short8*)(o + l * 8) = *(short8*)ov;
    }
}

__global__ void pack_NK_kernel(const float* __restrict__ src, unsigned short* __restrict__ dst,
                               int N, int K) {
    pack_NK_body(src, dst, N, K, blockIdx.x, blockIdx.y);
}

// ---------------- misc init body ----------------
__device__ __forceinline__ void init_misc_body(int i,
                                 const float* __restrict__ bq, const float* __restrict__ bk,
                                 const float* __restrict__ bv, float* __restrict__ bqkv,
                                 const float* __restrict__ cls, const float* __restrict__ pos,
                                 float* __restrict__ h) {
    if (i < DEPTH * 2304) {
        int L = i / 2304, j = i - L * 2304;
        float v = (j < 768) ? bq[L * 768 + j] : (j < 1536) ? bk[L * 768 + j - 768] : bv[L * 768 + j - 1536];
        bqkv[i] = v;
    }
    int j = i - DEPTH * 2304;
    if (j >= 0 && j < EMBED) h[j] = cls[j] + pos[j];
}

__global__ void init_misc_kernel(const float* __restrict__ bq, const float* __restrict__ bk,
                                 const float* __restrict__ bv, float* __restrict__ bqkv,
                                 const float* __restrict__ cls, const float* __restrict__ pos,
                                 float* __restrict__ h) {
    init_misc_body(blockIdx.x * 256 + threadIdx.x, bq, bk, bv, bqkv, cls, pos, h);
}

// ---------------- ONE upfront prep launch: all packs + conv pack + im2col + init ----------
// grid = 6*1728 (layer packs) + 192 (conv) + 2048 (im2col) + 57 (init) = 12665 blocks
__global__ void prep_mega_kernel(const float* __restrict__ x, const float* __restrict__ conv_w,
                                 const float* __restrict__ wq, const float* __restrict__ wk,
                                 const float* __restrict__ wv, const float* __restrict__ wo,
                                 const float* __restrict__ w1s, const float* __restrict__ w2s,
                                 const float* __restrict__ bq, const float* __restrict__ bk,
                                 const float* __restrict__ bv, const float* __restrict__ cls,
                                 const float* __restrict__ pos,
                                 unsigned short* __restrict__ patch_pk,
                                 unsigned short* __restrict__ convw_pk,
                                 float* __restrict__ bqkv, float* __restrict__ h,
                                 unsigned short* __restrict__ qkv_pk, unsigned short* __restrict__ o_pk,
                                 unsigned short* __restrict__ w1_pk, unsigned short* __restrict__ w2_pk) {
    const int fid = blockIdx.x;
    const size_t EE = (size_t)EMBED * EMBED, EM = (size_t)EMBED * MLP_DIM;
    if (fid < 6 * 1728) {
        const int lid = fid / 1728, r = fid % 1728;
        pack_piece(r, wq + lid * EE, wk + lid * EE, wv + lid * EE, wo + lid * EE,
                   w1s + lid * EM, w2s + lid * EM,
                   qkv_pk + (size_t)lid * 3 * EE, o_pk + lid * EE,
                   w1_pk + lid * EM, w2_pk + lid * EM);
    } else if (fid < 6 * 1728 + 192) {
        const int r = fid - 6 * 1728;
        pack_NK_body(conv_w, convw_pk, EMBED, 1024, r % 6, r / 6);
    } else if (fid < 6 * 1728 + 192 + 2048) {
        im2col_body(x, patch_pk, fid - (6 * 1728 + 192));
    } else {
        const int r = fid - (6 * 1728 + 192 + 2048);
        init_misc_body(r * 256 + threadIdx.x, bq, bk, bv, bqkv, cls, pos, h);
    }
}

// h[1+pi] = pos[1+pi] + sum_{c<4} tmp[c][pi]  (patch-embed partial merge)
__global__ void embed_add_kernel(const float* __restrict__ pos, const float* __restrict__ tmp,
                                 float* __restrict__ h) {
    int gid = blockIdx.x * 256 + threadIdx.x;
    if (gid >= 2048 * EMBED) return;
    float v = pos[EMBED + gid];
    #pragma unroll
    for (int c = 0; c < 4; ++c) v += tmp[(size_t)c * SP * EMBED + gid];
    h[EMBED + gid] = v;
}

// ---------------- layernorm (plain): one block per row; packed-bf16 (nkt=24) out ----------------
template<bool PACKED>
__global__ void ln_kernel(const float* __restrict__ in, void* __restrict__ outv,
                          const float* __restrict__ w, const float* __restrict__ b,
                          int M) {
    int row = blockIdx.x;
    if (row >= M) return;
    const float* xr = in + (size_t)row * EMBED;
    int tid = threadIdx.x;
    float v0 = xr[tid], v1 = xr[tid + 256], v2 = xr[tid + 512];
    __shared__ float red[4];
    float s = v0 + v1 + v2;
    #pragma unroll
    for (int o = 32; o > 0; o >>= 1) s += __shfl_down(s, o);
    if ((tid & 63) == 0) red[tid >> 6] = s;
    __syncthreads();
    float mean = (red[0] + red[1] + red[2] + red[3]) * (1.0f / 768.0f);
    __syncthreads();
    float d0 = v0 - mean, d1 = v1 - mean, d2 = v2 - mean;
    float q2 = d0 * d0 + d1 * d1 + d2 * d2;
    #pragma unroll
    for (int o = 32; o > 0; o >>= 1) q2 += __shfl_down(q2, o);
    if ((tid & 63) == 0) red[tid >> 6] = q2;
    __syncthreads();
    float var = (red[0] + red[1] + red[2] + red[3]) * (1.0f / 768.0f);
    float rstd = 1.0f / sqrtf(var + 1e-5f);
    float o0 = d0 * rstd * w[tid]       + b[tid];
    float o1 = d1 * rstd * w[tid + 256] + b[tid + 256];
    float o2 = d2 * rstd * w[tid + 512] + b[tid + 512];
    if (PACKED) {
        unsigned short* o = (unsigned short*)outv;
        o[pidx(row, tid,       24)] = f2bf(o0);
        o[pidx(row, tid + 256, 24)] = f2bf(o1);
        o[pidx(row, tid + 512, 24)] = f2bf(o2);
    } else {
        float* orow = (float*)outv + (size_t)row * EMBED;
        orow[tid] = o0; orow[tid + 256] = o1; orow[tid + 512] = o2;
    }
}

// ---------------- layernorm + fused residual: v = h + sum_{c<nt} tmp[c]; h = v; LN(v) ----------
template<bool PACKED>
__global__ void ln_res_kernel(float* __restrict__ h, const float* __restrict__ tmp, int nt,
                              void* __restrict__ outv,
                              const float* __restrict__ w, const float* __restrict__ b,
                              int M) {
    int row = blockIdx.x;
    if (row >= M) return;
    const size_t base = (size_t)row * EMBED;
    int tid = threadIdx.x;
    float v0 = h[base + tid], v1 = h[base + tid + 256], v2 = h[base + tid + 512];
    for (int c = 0; c < nt; ++c) {
        const float* tc = tmp + (size_t)c * SP * EMBED + base;
        v0 += tc[tid]; v1 += tc[tid + 256]; v2 += tc[tid + 512];
    }
    h[base + tid] = v0; h[base + tid + 256] = v1; h[base + tid + 512] = v2;
    __shared__ float red[4];
    float s = v0 + v1 + v2;
    #pragma unroll
    for (int o = 32; o > 0; o >>= 1) s += __shfl_down(s, o);
    if ((tid & 63) == 0) red[tid >> 6] = s;
    __syncthreads();
    float mean = (red[0] + red[1] + red[2] + red[3]) * (1.0f / 768.0f);
    __syncthreads();
    float d0 = v0 - mean, d1 = v1 - mean, d2 = v2 - mean;
    float q2 = d0 * d0 + d1 * d1 + d2 * d2;
    #pragma unroll
    for (int o = 32; o > 0; o >>= 1) q2 += __shfl_down(q2, o);
    if ((tid & 63) == 0) red[tid >> 6] = q2;
    __syncthreads();
    float var = (red[0] + red[1] + red[2] + red[3]) * (1.0f / 768.0f);
    float rstd = 1.0f / sqrtf(var + 1e-5f);
    float o0 = d0 * rstd * w[tid]       + b[tid];
    float o1 = d1 * rstd * w[tid + 256] + b[tid + 256];
    float o2 = d2 * rstd * w[tid + 512] + b[tid + 512];
    if (PACKED) {
        unsigned short* o = (unsigned short*)outv;
        o[pidx(row, tid,       24)] = f2bf(o0);
        o[pidx(row, tid + 256, 24)] = f2bf(o1);
        o[pidx(row, tid + 512, 24)] = f2bf(o2);
    } else {
        float* orow = (float*)outv + (size_t)row * EMBED;
        orow[tid] = o0; orow[tid + 256] = o1; orow[tid + 512] = o2;
    }
}

// ---------------- bf16 MFMA GEMM: LDS-free, fragment-packed, 128x128 block (2x2 waves) ----
// 1D grid with bijective XCD swizzle (m204), x-fastest work order for A-panel L2 locality.
// MODE 0: f32 partial store, chunk bz writes Cf + bz*SP*EMBED (N must be 768; bias chunk 0).
// MODE 2: bf16 row-major store. MODE 3: bf16 packed store. MODE 2/3 require nz == 1.
// No atomics (round-12/15: atomic-unit throughput was binding the accum GEMMs).
template<int ACT, int MODE>
__global__ __launch_bounds__(256)
void gemm_bf16(const unsigned short* __restrict__ Apk, const unsigned short* __restrict__ Bpk,
               const float* __restrict__ bias, void* __restrict__ Cv,
               int M, int N, int K, int nx, int ny, int nz) {
    // --- bijective XCD swizzle ---
    const int nwg = nx * ny * nz;
    const int fid = blockIdx.x;
    const int xcd = fid & 7, slot = fid >> 3;
    const int qq = nwg >> 3, rr2 = nwg & 7;
    const int orig = (xcd < rr2 ? xcd * (qq + 1) : rr2 * (qq + 1) + (xcd - rr2) * qq) + slot;
    const int bx = orig % nx;
    const int tzy = orig / nx;
    const int bz = tzy % nz;
    const int by = tzy / nz;

    const int tid = threadIdx.x;
    const int lane = tid & 63;
    const int w4 = tid >> 6;
    const int wm = w4 >> 1, wn = w4 & 1;
    const int row0 = by * 128 + wm * 64, col0 = bx * 128 + wn * 64;
    const int nktT = K >> 5;                       // total K tiles
    const int nk = nktT / nz;                      // tiles this chunk
    const int t0 = bz * nk;

    f32x4 acc[4][4];
    #pragma unroll
    for (int mi = 0; mi < 4; ++mi)
        #pragma unroll
        for (int ni = 0; ni < 4; ++ni)
            #pragma unroll
            for (int j = 0; j < 4; ++j) acc[mi][ni][j] = 0.0f;

    const unsigned short* Ab[4];
    const unsigned short* Bb[4];
    #pragma unroll
    for (int i = 0; i < 4; ++i) {
        Ab[i] = Apk + (((size_t)(by * 8 + wm * 4 + i) * nktT + t0) << 9) + lane * 8;
        Bb[i] = Bpk + (((size_t)(bx * 8 + wn * 4 + i) * nktT + t0) << 9) + lane * 8;
    }

    auto LOADT = [&](int t, short8* aa, short8* bb) {
        #pragma unroll
        for (int i = 0; i < 4; ++i) {
            aa[i] = *(const short8*)(Ab[i] + (size_t)t * 512);
            bb[i] = *(const short8*)(Bb[i] + (size_t)t * 512);
        }
    };
    auto MF = [&](short8* aa, short8* bb) {
        #pragma unroll
        for (int mi = 0; mi < 4; ++mi)
            #pragma unroll
            for (int ni = 0; ni < 4; ++ni)
                acc[mi][ni] = __builtin_amdgcn_mfma_f32_16x16x32_bf16(aa[mi], bb[ni], acc[mi][ni], 0, 0, 0);
    };

    short8 A0[4], B0[4], A1[4], B1[4];
    LOADT(0, A0, B0);
    for (int t = 0; t < nk; t += 2) {              // nk % 2 == 0
        LOADT(t + 1, A1, B1);
        MF(A0, B0);
        if (t + 2 < nk) LOADT(t + 2, A0, B0);
        MF(A1, B1);
    }

    float* Cf = (float*)Cv + (MODE == 0 ? (size_t)bz * SP * EMBED : 0);
    unsigned short* Cb = (unsigned short*)Cv;
    const int ln15 = lane & 15, kq = lane >> 4;
    const int nktN = N >> 5;
    const bool addb = (bz == 0);
    #pragma unroll
    for (int mi = 0; mi < 4; ++mi) {
        #pragma unroll
        for (int ni = 0; ni < 4; ++ni) {
            const int col = col0 + ni * 16 + ln15;
            const float bb = addb ? bias[col] : 0.0f;
            #pragma unroll
            for (int j = 0; j < 4; ++j) {
                const int row = row0 + mi * 16 + kq * 4 + j;
                if (row < M) {
                    float v = acc[mi][ni][j] + bb;
                    if (ACT == 1) v = fast_gelu(v);
                    if (MODE == 0)      Cf[(size_t)row * N + col] = v;
                    else if (MODE == 2) Cb[(size_t)row * N + col] = f2bf(v);
                    else                Cb[pidx(row, col, nktN)] = f2bf(v);
                }
            }
        }
    }
}

// ---------------- dilated attention: MFMA (bf16 qkv in, bf16 Obr out) ----------------
__global__ __launch_bounds__(256, 1)
void attn_kernel(const unsigned short* __restrict__ qkv,
                 unsigned short* __restrict__ Obr, float* __restrict__ Lbr) {
    const int bx = blockIdx.x, hh = blockIdx.y;
    int b, n;
    if      (bx < 17) { b = 0; n = bx; }
    else if (bx < 26) { b = 1; n = bx - 17; }
    else if (bx < 31) { b = 2; n = bx - 26; }
    else if (bx < 34) { b = 3; n = bx - 31; }
    else              { b = 4; n = bx - 34; }
    const int r = 1 << b;
    const int segw = 128 << b;
    const int base = n * segw + (hh & (r - 1));

    __shared__ __attribute__((aligned(16))) unsigned short VT[64 * 128];   // [d][k] swizzled
    __shared__ __attribute__((aligned(16))) unsigned short Pl[128 * 128];  // [q][k] swizzled

    const int tid = threadIdx.x;

    // ---- stage V^T (transposed + swizzled) ----
    {
        const int key = tid >> 1, dh2 = (tid & 1) * 32;
        const int pos = base + r * key;
        const bool val = pos < N_REAL;
        const unsigned short* vsrc = qkv + (size_t)(val ? pos : 0) * 2304 + 1536 + hh * 64 + dh2;
        #pragma unroll
        for (int u = 0; u < 4; ++u) {
            short8 vv = ((const short8*)vsrc)[u];
            #pragma unroll
            for (int e = 0; e < 8; ++e) {
                const int d = dh2 + u * 8 + e;
                VT[(d * 256 + ((key * 2) ^ ((d & 7) << 4))) >> 1] =
                    val ? (unsigned short)vv[e] : (unsigned short)0;
            }
        }
    }
    __syncthreads();

    const int lane = tid & 63, wv = tid >> 6;
    const int ln15 = lane & 15, kq = lane >> 4;

    // ---- QK^T ----
    f32x4 sc[2][8];
    #pragma unroll
    for (int mi = 0; mi < 2; ++mi)
        #pragma unroll
        for (int ni = 0; ni < 8; ++ni)
            #pragma unroll
            for (int j = 0; j < 4; ++j) sc[mi][ni][j] = 0.0f;

    #pragma unroll
    for (int kt = 0; kt < 2; ++kt) {
        short8 qfr[2], kfr[8];
        #pragma unroll
        for (int mi = 0; mi < 2; ++mi) {
            const int pos = base + r * (wv * 32 + mi * 16 + ln15);
            qfr[mi] = *(const short8*)(qkv + (size_t)(pos < N_REAL ? pos : 0) * 2304
                                       + hh * 64 + kt * 32 + kq * 8);
        }
        #pragma unroll
        for (int ni = 0; ni < 8; ++ni) {
            const int pos = base + r * (ni * 16 + ln15);
            kfr[ni] = *(const short8*)(qkv + (size_t)(pos < N_REAL ? pos : 0) * 2304
                                       + 768 + hh * 64 + kt * 32 + kq * 8);
        }
        #pragma unroll
        for (int mi = 0; mi < 2; ++mi)
            #pragma unroll
            for (int ni = 0; ni < 8; ++ni)
                sc[mi][ni] = __builtin_amdgcn_mfma_f32_16x16x32_bf16(qfr[mi], kfr[ni], sc[mi][ni], 0, 0, 0);
    }

    // scale + key mask
    #pragma unroll
    for (int ni = 0; ni < 8; ++ni) {
        const bool kval = (base + r * (ni * 16 + ln15)) < N_REAL;
        #pragma unroll
        for (int mi = 0; mi < 2; ++mi)
            #pragma unroll
            for (int j = 0; j < 4; ++j)
                sc[mi][ni][j] = kval ? sc[mi][ni][j] * 0.125f : NEGV;
    }

    // ---- wave-local row softmax ----
    float rsum[2][4];
    #pragma unroll
    for (int mi = 0; mi < 2; ++mi) {
        #pragma unroll
        for (int j = 0; j < 4; ++j) {
            float mx = sc[mi][0][j];
            #pragma unroll
            for (int ni = 1; ni < 8; ++ni) mx = fmaxf(mx, sc[mi][ni][j]);
            mx = fmaxf(mx, __shfl_xor(mx, 1));
            mx = fmaxf(mx, __shfl_xor(mx, 2));
            mx = fmaxf(mx, __shfl_xor(mx, 4));
            mx = fmaxf(mx, __shfl_xor(mx, 8));
            float sm = 0.f;
            #pragma unroll
            for (int ni = 0; ni < 8; ++ni) {
                float e = __expf(sc[mi][ni][j] - mx);
                sc[mi][ni][j] = e;
                sm += e;
            }
            sm += __shfl_xor(sm, 1);
            sm += __shfl_xor(sm, 2);
            sm += __shfl_xor(sm, 4);
            sm += __shfl_xor(sm, 8);
            rsum[mi][j] = sm;
            const int prow = wv * 32 + mi * 16 + kq * 4 + j;
            const int qpos = base + r * prow;
            if (ln15 == 0 && qpos < N_REAL)
                Lbr[((size_t)b * SP + qpos) * HEADS + hh] = mx + logf(sm);
        }
    }

    // ---- write P to LDS (bf16, swizzled) ----
    #pragma unroll
    for (int mi = 0; mi < 2; ++mi)
        #pragma unroll
        for (int j = 0; j < 4; ++j) {
            const int prow = wv * 32 + mi * 16 + kq * 4 + j;
            #pragma unroll
            for (int ni = 0; ni < 8; ++ni) {
                const int col = ni * 16 + ln15;
                Pl[(prow * 256 + ((col * 2) ^ ((prow & 7) << 4))) >> 1] = f2bf(sc[mi][ni][j]);
            }
        }
    __syncthreads();

    // ---- PV: O[32 q][64 d] per wave, K=128 ----
    f32x4 ov[2][4];
    #pragma unroll
    for (int mi = 0; mi < 2; ++mi)
        #pragma unroll
        for (int ni = 0; ni < 4; ++ni)
            #pragma unroll
            for (int j = 0; j < 4; ++j) ov[mi][ni][j] = 0.0f;

    #pragma unroll
    for (int kt = 0; kt < 4; ++kt) {
        short8 pa[2], vb[4];
        #pragma unroll
        for (int mi = 0; mi < 2; ++mi) {
            const int row = wv * 32 + mi * 16 + ln15;
            pa[mi] = *(const short8*)((const char*)Pl + row * 256
                                      + ((kt * 64 + kq * 16) ^ ((row & 7) << 4)));
        }
        #pragma unroll
        for (int ni = 0; ni < 4; ++ni) {
            const int d = ni * 16 + ln15;
            vb[ni] = *(const short8*)((const char*)VT + d * 256
                                      + ((kt * 64 + kq * 16) ^ ((d & 7) << 4)));
        }
        #pragma unroll
        for (int mi = 0; mi < 2; ++mi)
            #pragma unroll
            for (int ni = 0; ni < 4; ++ni)
                ov[mi][ni] = __builtin_amdgcn_mfma_f32_16x16x32_bf16(pa[mi], vb[ni], ov[mi][ni], 0, 0, 0);
    }

    // ---- epilogue: normalize + store ----
    #pragma unroll
    for (int mi = 0; mi < 2; ++mi)
        #pragma unroll
        for (int j = 0; j < 4; ++j) {
            const int prow = wv * 32 + mi * 16 + kq * 4 + j;
            const int qpos = base + r * prow;
            if (qpos < N_REAL) {
                const float inv = 1.0f / rsum[mi][j];
                #pragma unroll
                for (int ni = 0; ni < 4; ++ni)
                    Obr[((size_t)b * N_REAL + qpos) * EMBED + hh * 64 + ni * 16 + ln15] =
                        f2bf(ov[mi][ni][j] * inv);
            }
        }
}

// ---------------- branch combine -> packed bf16 (A-layout, nkt=24) ----------------
__global__ void combine_kernel(const unsigned short* __restrict__ Obr, const float* __restrict__ Lbr,
                               unsigned short* __restrict__ out) {
    int gid = blockIdx.x * 256 + threadIdx.x;
    if (gid >= N_REAL * EMBED) return;
    int p = gid / EMBED, e = gid - p * EMBED;
    int h = e >> 6;
    float l[5];
    float mx = NEGV;
    #pragma unroll
    for (int b = 0; b < 5; ++b) {
        const int rm = (1 << b) - 1;
        l[b] = ((p & rm) == (h & rm)) ? Lbr[((size_t)b * SP + p) * HEADS + h] : NEGV;
        mx = fmaxf(mx, l[b]);
    }
    float wsum = 0.f, acc = 0.f;
    #pragma unroll
    for (int b = 0; b < 5; ++b) {
        if (l[b] > NEGV * 0.5f) {
            float wt = expf(l[b] - mx);
            wsum += wt;
            acc += wt * bf2f(Obr[((size_t)b * N_REAL + p) * EMBED + e]);
        }
    }
    out[pidx(p, e, 24)] = f2bf(acc / wsum);
}

// ---------------- host orchestration ----------------
extern "C" void kernel_launch(void* const* d_in, const int* in_sizes, int n_in,
                              void* d_out, int out_size, void* d_ws, size_t ws_size,
                              hipStream_t stream) {
    const float* x      = (const float*)d_in[0];
    const float* conv_w = (const float*)d_in[1];
    const float* conv_b = (const float*)d_in[2];
    const float* cls    = (const float*)d_in[3];
    const float* pos    = (const float*)d_in[4];
    const float* ln1w   = (const float*)d_in[5];
    const float* ln1b   = (const float*)d_in[6];
    const float* wq     = (const float*)d_in[7];
    const float* bq     = (const float*)d_in[8];
    const float* wk     = (const float*)d_in[9];
    const float* bk     = (const float*)d_in[10];
    const float* wv     = (const float*)d_in[11];
    const float* bv     = (const float*)d_in[12];
    const float* wo     = (const float*)d_in[13];
    const float* bo     = (const float*)d_in[14];
    const float* ln2w   = (const float*)d_in[15];
    const float* ln2b   = (const float*)d_in[16];
    const float* w1     = (const float*)d_in[17];
    const float* b1     = (const float*)d_in[18];
    const float* w2     = (const float*)d_in[19];
    const float* b2     = (const float*)d_in[20];
    const float* lnfw   = (const float*)d_in[21];
    const float* lnfb   = (const float*)d_in[22];

    const size_t EE = (size_t)EMBED * EMBED;
    const size_t EM = (size_t)EMBED * MLP_DIM;

    // decide upfront vs per-layer weight packing based on ws_size (host-side, deterministic)
    const size_t base_floats =
        (size_t)SP * EMBED + 4 * (size_t)SP * EMBED + 5 * (size_t)SP * HEADS
        + (size_t)DEPTH * 2304 + (size_t)SPAD * 2304 / 2 + (size_t)SPAD * EMBED / 2
        + (size_t)SPAD * EMBED / 2 + (size_t)SPAD * MLP_DIM / 2 + (size_t)2112 * 1024 / 2
        + (size_t)EMBED * 1024 / 2 + ((size_t)5 * N_REAL * EMBED / 2 + 64);
    const size_t per_layer_floats = (3 * EE + EE + EM + EM) / 2;
    const bool up = ws_size >= (base_floats + 6 * per_layer_floats) * 4 + (1 << 20);
    const int NL = up ? DEPTH : 1;

    float* ws = (float*)d_ws;
    float* h     = ws;  ws += (size_t)SP * EMBED;
    float* tmp   = ws;  ws += (size_t)4 * SP * EMBED;
    float* Lbr   = ws;  ws += (size_t)5 * SP * HEADS;
    float* bqkv  = ws;  ws += (size_t)DEPTH * 2304;
    unsigned short* qkv_bf   = (unsigned short*)ws;  ws += (size_t)SPAD * 2304 / 2;
    unsigned short* xln_pk   = (unsigned short*)ws;  ws += (size_t)SPAD * EMBED / 2;
    unsigned short* attn_pk  = (unsigned short*)ws;  ws += (size_t)SPAD * EMBED / 2;
    unsigned short* mid_pk   = (unsigned short*)ws;  ws += (size_t)SPAD * MLP_DIM / 2;
    unsigned short* patch_pk = (unsigned short*)ws;  ws += (size_t)2112 * 1024 / 2;
    unsigned short* convw_pk = (unsigned short*)ws;  ws += (size_t)EMBED * 1024 / 2;
    unsigned short* Obr      = (unsigned short*)ws;  ws += (size_t)5 * N_REAL * EMBED / 2 + 64;
    unsigned short* wqkv_pk  = (unsigned short*)ws;  ws += (size_t)NL * 3 * EE / 2;
    unsigned short* wo_pk    = (unsigned short*)ws;  ws += (size_t)NL * EE / 2;
    unsigned short* w1_pk    = (unsigned short*)ws;  ws += (size_t)NL * EM / 2;
    unsigned short* w2_pk    = (unsigned short*)ws;  ws += (size_t)NL * EM / 2;

    // ---- upfront packing / init ----
    if (up) {
        prep_mega_kernel<<<6 * 1728 + 192 + 2048 + 57, 256, 0, stream>>>(
            x, conv_w, wq, wk, wv, wo, w1, w2, bq, bk, bv, cls, pos,
            patch_pk, convw_pk, bqkv, h, wqkv_pk, wo_pk, w1_pk, w2_pk);
    } else {
        im2col_kernel<<<2048, 256, 0, stream>>>(x, patch_pk);
        pack_NK_kernel<<<dim3(6, 32), 256, 0, stream>>>(conv_w, convw_pk, EMBED, 1024);
        init_misc_kernel<<<(DEPTH * 2304 + EMBED + 255) / 256, 256, 0, stream>>>(
            bq, bk, bv, bqkv, cls, pos, h);
    }
    // patch GEMM -> 4 f32 partials, then merge with pos
    gemm_bf16<0, 0><<<384, 256, 0, stream>>>(patch_pk, convw_pk, conv_b,
                                             tmp, 2048, EMBED, 1024, 6, 16, 4);
    embed_add_kernel<<<(2048 * EMBED + 255) / 256, 256, 0, stream>>>(pos, tmp, h);

    for (int L = 0; L < DEPTH; ++L) {
        const int off = up ? L : 0;
        unsigned short* qkvW = wqkv_pk + (size_t)off * 3 * EE;
        unsigned short* woW  = wo_pk   + (size_t)off * EE;
        unsigned short* w1W  = w1_pk   + (size_t)off * EM;
        unsigned short* w2W  = w2_pk   + (size_t)off * EM;
        if (!up)
            pack_all_kernel<<<1728, 256, 0, stream>>>(wq + L * EE, wk + L * EE, wv + L * EE,
                                                      wo + L * EE, w1 + L * EM, w2 + L * EM,
                                                      qkvW, woW, w1W, w2W);

        // LN1 -> packed bf16 (layer 0: h final; layers 1..5: fold prev MLP2's 4 partials)
        if (L == 0)
            ln_kernel<true><<<N_REAL, 256, 0, stream>>>(h, xln_pk, ln1w + (size_t)L * EMBED,
                                                        ln1b + (size_t)L * EMBED, N_REAL);
        else
            ln_res_kernel<true><<<N_REAL, 256, 0, stream>>>(h, tmp, 4, xln_pk,
                                                            ln1w + (size_t)L * EMBED,
                                                            ln1b + (size_t)L * EMBED, N_REAL);
        // fused QKV -> row-major bf16
        gemm_bf16<0, 2><<<306, 256, 0, stream>>>(xln_pk, qkvW, bqkv + (size_t)L * 2304,
                                                 qkv_bf, N_REAL, 2304, EMBED, 18, 17, 1);
        // dilated attention (MFMA)
        attn_kernel<<<dim3(36, 12), 256, 0, stream>>>(qkv_bf, Obr, Lbr);
        combine_kernel<<<((N_REAL * EMBED) + 255) / 256, 256, 0, stream>>>(Obr, Lbr, attn_pk);
        // O-projection -> 4 f32 partials
        gemm_bf16<0, 0><<<408, 256, 0, stream>>>(attn_pk, woW, bo + (size_t)L * EMBED,
                                                 tmp, N_REAL, EMBED, EMBED, 6, 17, 4);
        // LN2 folds O-proj partials into h -> packed bf16
        ln_res_kernel<true><<<N_REAL, 256, 0, stream>>>(h, tmp, 4, xln_pk,
                                                        ln2w + (size_t)L * EMBED,
                                                        ln2b + (size_t)L * EMBED, N_REAL);
        gemm_bf16<1, 3><<<408, 256, 0, stream>>>(xln_pk, w1W, b1 + (size_t)L * MLP_DIM,
                                                 mid_pk, N_REAL, MLP_DIM, EMBED, 24, 17, 1);
        // MLP2 -> 4 f32 partials (folded by next LN1 / final LN)
        gemm_bf16<0, 0><<<408, 256, 0, stream>>>(mid_pk, w2W, b2 + (size_t)L * EMBED,
                                                 tmp, N_REAL, EMBED, MLP_DIM, 6, 17, 4);
    }

    // final LN on row 0 (folds last MLP2 partials) -> d_out (768 fp32)
    ln_res_kernel<false><<<1, 256, 0, stream>>>(h, tmp, 4, (float*)d_out, lnfw, lnfb, 1);
}

// Round 19
// 905.987 us; speedup vs baseline: 1.0344x; 1.0040x over previous
//
#include <hip/hip_runtime.h>
#include <math.h>

#define EMBED 768
#define HEADS 12
#define DH 64
#define DEPTH 6
#define MLP_DIM 3072
#define N_REAL 2049
#define SP 2112            // fp32 buffer row padding (33*64)
#define SPAD 2176          // bf16 activation row padding (17*128)
#define NEGV (-1e9f)

typedef __attribute__((ext_vector_type(8))) short short8;
typedef __attribute__((ext_vector_type(4))) float f32x4;

__device__ __forceinline__ unsigned short f2bf(float f) {
    union { float f; unsigned u; } x; x.f = f;
    unsigned r = x.u + 0x7FFF + ((x.u >> 16) & 1);
    return (unsigned short)(r >> 16);
}
__device__ __forceinline__ float bf2f(unsigned short s) {
    union { unsigned u; float f; } x; x.u = (unsigned)s << 16;
    return x.f;
}

// fast exact-GELU: erf via Abramowitz-Stegun 7.1.26 (|err| <= 1.5e-7) + __expf
__device__ __forceinline__ float fast_gelu(float v) {
    const float ax = fabsf(v) * 0.70710678118654752f;
    const float tt = 1.0f / (1.0f + 0.3275911f * ax);
    const float poly = tt * (0.254829592f + tt * (-0.284496736f + tt * (1.421413741f
                       + tt * (-1.453152027f + tt * 1.061405429f))));
    float er = 1.0f - poly * __expf(-ax * ax);
    er = (v < 0.0f) ? -er : er;
    return 0.5f * v * (1.0f + er);
}

// packed fragment-blob index: blobs of 16 "major" (row for A / col for B) x 32 k.
// entry (l*8+e) of blob = element (major = l&15, k = (l>>4)*8 + e).
__device__ __forceinline__ size_t pidx(int mj, int k, int nkt) {
    return (((size_t)(mj >> 4) * nkt + (k >> 5)) << 9) + (size_t)((((k >> 3) & 3) * 16 + (mj & 15)) * 8 + (k & 7));
}

// ---------------- im2col body: one patch row -> packed blobs (A-layout, nkt=32) ------------
__device__ __forceinline__ void im2col_body(const float* __restrict__ x,
                                            unsigned short* __restrict__ p, int pi) {
    const int d = pi >> 8, rr = (pi >> 4) & 15, cc = pi & 15;
    const int t = threadIdx.x;            // 256
    #pragma unroll
    for (int u = 0; u < 4; ++u) {
        int i = u * 256 + t;              // 0..1023
        int kd = i >> 8, kr = (i >> 4) & 15, kc = i & 15;
        float v = x[(size_t)(d * 4 + kd) * 65536 + (rr * 16 + kr) * 256 + (cc * 16 + kc)];
        p[pidx(pi, i, 32)] = f2bf(v);
    }
}

__global__ void im2col_kernel(const float* __restrict__ x, unsigned short* __restrict__ p) {
    im2col_body(x, p, blockIdx.x);
}

// ---------------- weight pack: fp32 [K][N] -> fragment blobs (B-layout) ----------------
// LDS layout: row r (=output col), k-index kk stored at column (kk + 4*(r>>4)) & 31.
// Write bank = (20*ch + u + kk) % 32 -> exactly 2 lanes/bank (free). Reader inverts rotation.
__device__ __forceinline__ void pack_KN_body(const float* __restrict__ src,
                                             unsigned short* __restrict__ dst,
                                             int N, int K, int bn, int bk) {
    __shared__ float lf[128][33];         // [n][k-rotated]
    const int t = threadIdx.x;
    {
        const int kk = t >> 3, ch = t & 7;
        const float4* s = (const float4*)(src + (size_t)(bk * 32 + kk) * N + bn * 128 + ch * 16);
        float4 v0 = s[0], v1 = s[1], v2 = s[2], v3 = s[3];
        float tmp[16];
        ((float4*)tmp)[0] = v0; ((float4*)tmp)[1] = v1; ((float4*)tmp)[2] = v2; ((float4*)tmp)[3] = v3;
        const int cidx = (kk + 4 * ch) & 31;
        #pragma unroll
        for (int u = 0; u < 16; ++u) lf[ch * 16 + u][cidx] = tmp[u];
    }
    __syncthreads();
    const int nkt = K >> 5;
    const int cg = t >> 5;                // blob 0..7
    const int l0 = (t & 31) * 2;
    const int rot = 4 * cg;               // col>>4 == cg for this thread's cols
    unsigned short* o = dst + (((size_t)(bn * 8 + cg) * nkt + bk) << 9);
    #pragma unroll
    for (int q = 0; q < 2; ++q) {
        const int l = l0 + q;
        const int col = cg * 16 + (l & 15), kb = (l >> 4) * 8;
        unsigned short ov[8];
        #pragma unroll
        for (int e = 0; e < 8; ++e) ov[e] = f2bf(lf[col][(kb + e + rot) & 31]);
        *(short8*)(o + l * 8) = *(short8*)ov;
    }
}

// per-layer piece dispatch (r in [0,1728))
__device__ __forceinline__ void pack_piece(int r,
                                           const float* wq, const float* wk,
                                           const float* wv, const float* wo,
                                           const float* w1s, const float* w2s,
                                           unsigned short* qkv_pk, unsigned short* o_pk,
                                           unsigned short* w1_pk, unsigned short* w2_pk) {
    if (r < 576) {
        const int m = r / 144, rr = r % 144;
        const float* src = (m == 0) ? wq : (m == 1) ? wk : (m == 2) ? wv : wo;
        unsigned short* dst = (m < 3) ? qkv_pk + (size_t)m * EMBED * EMBED : o_pk;
        pack_KN_body(src, dst, EMBED, EMBED, rr % 6, rr / 6);
    } else if (r < 1152) {
        const int rr = r - 576;
        pack_KN_body(w1s, w1_pk, MLP_DIM, EMBED, rr % 24, rr / 24);
    } else {
        const int rr = r - 1152;
        pack_KN_body(w2s, w2_pk, EMBED, MLP_DIM, rr % 6, rr / 6);
    }
}

// one layer per launch (fallback path)
__global__ void pack_all_kernel(const float* __restrict__ wq, const float* __restrict__ wk,
                                const float* __restrict__ wv, const float* __restrict__ wo,
                                const float* __restrict__ w1s, const float* __restrict__ w2s,
                                unsigned short* __restrict__ qkv_pk, unsigned short* __restrict__ o_pk,
                                unsigned short* __restrict__ w1_pk, unsigned short* __restrict__ w2_pk) {
    pack_piece(blockIdx.x, wq, wk, wv, wo, w1s, w2s, qkv_pk, o_pk, w1_pk, w2_pk);
}

// pack from fp32 [N][K] body (conv_w: [768][1024]); write bank already 2-way (free)
__device__ __forceinline__ void pack_NK_body(const float* __restrict__ src,
                                             unsigned short* __restrict__ dst,
                                             int N, int K, int bn, int bk) {
    __shared__ float lf[128][33];
    const int t = threadIdx.x;
    {
        const int row = t >> 1, hf = t & 1;
        const float4* s = (const float4*)(src + (size_t)(bn * 128 + row) * K + bk * 32 + hf * 16);
        float4 v0 = s[0], v1 = s[1], v2 = s[2], v3 = s[3];
        float tmp[16];
        ((float4*)tmp)[0] = v0; ((float4*)tmp)[1] = v1; ((float4*)tmp)[2] = v2; ((float4*)tmp)[3] = v3;
        #pragma unroll
        for (int u = 0; u < 16; ++u) lf[row][hf * 16 + u] = tmp[u];
    }
    __syncthreads();
    const int nkt = K >> 5;
    const int cg = t >> 5;
    const int l0 = (t & 31) * 2;
    unsigned short* o = dst + (((size_t)(bn * 8 + cg) * nkt + bk) << 9);
    #pragma unroll
    for (int q = 0; q < 2; ++q) {
        const int l = l0 + q;
        const int col = cg * 16 + (l & 15), kb = (l >> 4) * 8;
        unsigned short ov[8];
        #pragma unroll
        for (int e = 0; e < 8; ++e) ov[e] = f2bf(lf[col][kb + e]);
        *(short8*)(o + l * 8) = *(short8*)ov;
    }
}

__global__ void pack_NK_kernel(const float* __restrict__ src, unsigned short* __restrict__ dst,
                               int N, int K) {
    pack_NK_body(src, dst, N, K, blockIdx.x, blockIdx.y);
}

// ---------------- misc init body ----------------
__device__ __forceinline__ void init_misc_body(int i,
                                 const float* __restrict__ bq, const float* __restrict__ bk,
                                 const float* __restrict__ bv, float* __restrict__ bqkv,
                                 const float* __restrict__ cls, const float* __restrict__ pos,
                                 float* __restrict__ h) {
    if (i < DEPTH * 2304) {
        int L = i / 2304, j = i - L * 2304;
        float v = (j < 768) ? bq[L * 768 + j] : (j < 1536) ? bk[L * 768 + j - 768] : bv[L * 768 + j - 1536];
        bqkv[i] = v;
    }
    int j = i - DEPTH * 2304;
    if (j >= 0 && j < EMBED) h[j] = cls[j] + pos[j];
}

__global__ void init_misc_kernel(const float* __restrict__ bq, const float* __restrict__ bk,
                                 const float* __restrict__ bv, float* __restrict__ bqkv,
                                 const float* __restrict__ cls, const float* __restrict__ pos,
                                 float* __restrict__ h) {
    init_misc_body(blockIdx.x * 256 + threadIdx.x, bq, bk, bv, bqkv, cls, pos, h);
}

// ---------------- ONE upfront prep launch: all packs + conv pack + im2col + init ----------
// grid = 6*1728 (layer packs) + 192 (conv) + 2048 (im2col) + 57 (init) = 12665 blocks
__global__ void prep_mega_kernel(const float* __restrict__ x, const float* __restrict__ conv_w,
                                 const float* __restrict__ wq, const float* __restrict__ wk,
                                 const float* __restrict__ wv, const float* __restrict__ wo,
                                 const float* __restrict__ w1s, const float* __restrict__ w2s,
                                 const float* __restrict__ bq, const float* __restrict__ bk,
                                 const float* __restrict__ bv, const float* __restrict__ cls,
                                 const float* __restrict__ pos,
                                 unsigned short* __restrict__ patch_pk,
                                 unsigned short* __restrict__ convw_pk,
                                 float* __restrict__ bqkv, float* __restrict__ h,
                                 unsigned short* __restrict__ qkv_pk, unsigned short* __restrict__ o_pk,
                                 unsigned short* __restrict__ w1_pk, unsigned short* __restrict__ w2_pk) {
    const int fid = blockIdx.x;
    const size_t EE = (size_t)EMBED * EMBED, EM = (size_t)EMBED * MLP_DIM;
    if (fid < 6 * 1728) {
        const int lid = fid / 1728, r = fid % 1728;
        pack_piece(r, wq + lid * EE, wk + lid * EE, wv + lid * EE, wo + lid * EE,
                   w1s + lid * EM, w2s + lid * EM,
                   qkv_pk + (size_t)lid * 3 * EE, o_pk + lid * EE,
                   w1_pk + lid * EM, w2_pk + lid * EM);
    } else if (fid < 6 * 1728 + 192) {
        const int r = fid - 6 * 1728;
        pack_NK_body(conv_w, convw_pk, EMBED, 1024, r % 6, r / 6);
    } else if (fid < 6 * 1728 + 192 + 2048) {
        im2col_body(x, patch_pk, fid - (6 * 1728 + 192));
    } else {
        const int r = fid - (6 * 1728 + 192 + 2048);
        init_misc_body(r * 256 + threadIdx.x, bq, bk, bv, bqkv, cls, pos, h);
    }
}

// h[1+pi] = pos[1+pi] + sum_{c<4} tmp[c][pi]  (patch-embed partial merge)
__global__ void embed_add_kernel(const float* __restrict__ pos, const float* __restrict__ tmp,
                                 float* __restrict__ h) {
    int gid = blockIdx.x * 256 + threadIdx.x;
    if (gid >= 2048 * EMBED) return;
    float v = pos[EMBED + gid];
    #pragma unroll
    for (int c = 0; c < 4; ++c) v += tmp[(size_t)c * SP * EMBED + gid];
    h[EMBED + gid] = v;
}

// ---------------- layernorm (plain): one block per row; packed-bf16 (nkt=24) out ----------------
template<bool PACKED>
__global__ void ln_kernel(const float* __restrict__ in, void* __restrict__ outv,
                          const float* __restrict__ w, const float* __restrict__ b,
                          int M) {
    int row = blockIdx.x;
    if (row >= M) return;
    const float* xr = in + (size_t)row * EMBED;
    int tid = threadIdx.x;
    float v0 = xr[tid], v1 = xr[tid + 256], v2 = xr[tid + 512];
    __shared__ float red[4];
    float s = v0 + v1 + v2;
    #pragma unroll
    for (int o = 32; o > 0; o >>= 1) s += __shfl_down(s, o);
    if ((tid & 63) == 0) red[tid >> 6] = s;
    __syncthreads();
    float mean = (red[0] + red[1] + red[2] + red[3]) * (1.0f / 768.0f);
    __syncthreads();
    float d0 = v0 - mean, d1 = v1 - mean, d2 = v2 - mean;
    float q2 = d0 * d0 + d1 * d1 + d2 * d2;
    #pragma unroll
    for (int o = 32; o > 0; o >>= 1) q2 += __shfl_down(q2, o);
    if ((tid & 63) == 0) red[tid >> 6] = q2;
    __syncthreads();
    float var = (red[0] + red[1] + red[2] + red[3]) * (1.0f / 768.0f);
    float rstd = 1.0f / sqrtf(var + 1e-5f);
    float o0 = d0 * rstd * w[tid]       + b[tid];
    float o1 = d1 * rstd * w[tid + 256] + b[tid + 256];
    float o2 = d2 * rstd * w[tid + 512] + b[tid + 512];
    if (PACKED) {
        unsigned short* o = (unsigned short*)outv;
        o[pidx(row, tid,       24)] = f2bf(o0);
        o[pidx(row, tid + 256, 24)] = f2bf(o1);
        o[pidx(row, tid + 512, 24)] = f2bf(o2);
    } else {
        float* orow = (float*)outv + (size_t)row * EMBED;
        orow[tid] = o0; orow[tid + 256] = o1; orow[tid + 512] = o2;
    }
}

// ---------------- layernorm + fused residual: v = h + sum_{c<nt} tmp[c]; h = v; LN(v) ----------
template<bool PACKED>
__global__ void ln_res_kernel(float* __restrict__ h, const float* __restrict__ tmp, int nt,
                              void* __restrict__ outv,
                              const float* __restrict__ w, const float* __restrict__ b,
                              int M) {
    int row = blockIdx.x;
    if (row >= M) return;
    const size_t base = (size_t)row * EMBED;
    int tid = threadIdx.x;
    float v0 = h[base + tid], v1 = h[base + tid + 256], v2 = h[base + tid + 512];
    for (int c = 0; c < nt; ++c) {
        const float* tc = tmp + (size_t)c * SP * EMBED + base;
        v0 += tc[tid]; v1 += tc[tid + 256]; v2 += tc[tid + 512];
    }
    h[base + tid] = v0; h[base + tid + 256] = v1; h[base + tid + 512] = v2;
    __shared__ float red[4];
    float s = v0 + v1 + v2;
    #pragma unroll
    for (int o = 32; o > 0; o >>= 1) s += __shfl_down(s, o);
    if ((tid & 63) == 0) red[tid >> 6] = s;
    __syncthreads();
    float mean = (red[0] + red[1] + red[2] + red[3]) * (1.0f / 768.0f);
    __syncthreads();
    float d0 = v0 - mean, d1 = v1 - mean, d2 = v2 - mean;
    float q2 = d0 * d0 + d1 * d1 + d2 * d2;
    #pragma unroll
    for (int o = 32; o > 0; o >>= 1) q2 += __shfl_down(q2, o);
    if ((tid & 63) == 0) red[tid >> 6] = q2;
    __syncthreads();
    float var = (red[0] + red[1] + red[2] + red[3]) * (1.0f / 768.0f);
    float rstd = 1.0f / sqrtf(var + 1e-5f);
    float o0 = d0 * rstd * w[tid]       + b[tid];
    float o1 = d1 * rstd * w[tid + 256] + b[tid + 256];
    float o2 = d2 * rstd * w[tid + 512] + b[tid + 512];
    if (PACKED) {
        unsigned short* o = (unsigned short*)outv;
        o[pidx(row, tid,       24)] = f2bf(o0);
        o[pidx(row, tid + 256, 24)] = f2bf(o1);
        o[pidx(row, tid + 512, 24)] = f2bf(o2);
    } else {
        float* orow = (float*)outv + (size_t)row * EMBED;
        orow[tid] = o0; orow[tid + 256] = o1; orow[tid + 512] = o2;
    }
}

// ---------------- bf16 MFMA GEMM: LDS-free, fragment-packed, 128x128 block (2x2 waves) ----
// 1D grid with bijective XCD swizzle (m204), x-fastest work order for A-panel L2 locality.
// MODE 0: f32 partial store, chunk bz writes Cf + bz*SP*EMBED (N must be 768; bias chunk 0).
// MODE 2: bf16 row-major store. MODE 3: bf16 packed store. MODE 2/3 require nz == 1.
// No atomics (round-12/15: atomic-unit throughput was binding the accum GEMMs).
template<int ACT, int MODE>
__global__ __launch_bounds__(256)
void gemm_bf16(const unsigned short* __restrict__ Apk, const unsigned short* __restrict__ Bpk,
               const float* __restrict__ bias, void* __restrict__ Cv,
               int M, int N, int K, int nx, int ny, int nz) {
    // --- bijective XCD swizzle ---
    const int nwg = nx * ny * nz;
    const int fid = blockIdx.x;
    const int xcd = fid & 7, slot = fid >> 3;
    const int qq = nwg >> 3, rr2 = nwg & 7;
    const int orig = (xcd < rr2 ? xcd * (qq + 1) : rr2 * (qq + 1) + (xcd - rr2) * qq) + slot;
    const int bx = orig % nx;
    const int tzy = orig / nx;
    const int bz = tzy % nz;
    const int by = tzy / nz;

    const int tid = threadIdx.x;
    const int lane = tid & 63;
    const int w4 = tid >> 6;
    const int wm = w4 >> 1, wn = w4 & 1;
    const int row0 = by * 128 + wm * 64, col0 = bx * 128 + wn * 64;
    const int nktT = K >> 5;                       // total K tiles
    const int nk = nktT / nz;                      // tiles this chunk
    const int t0 = bz * nk;

    f32x4 acc[4][4];
    #pragma unroll
    for (int mi = 0; mi < 4; ++mi)
        #pragma unroll
        for (int ni = 0; ni < 4; ++ni)
            #pragma unroll
            for (int j = 0; j < 4; ++j) acc[mi][ni][j] = 0.0f;

    const unsigned short* Ab[4];
    const unsigned short* Bb[4];
    #pragma unroll
    for (int i = 0; i < 4; ++i) {
        Ab[i] = Apk + (((size_t)(by * 8 + wm * 4 + i) * nktT + t0) << 9) + lane * 8;
        Bb[i] = Bpk + (((size_t)(bx * 8 + wn * 4 + i) * nktT + t0) << 9) + lane * 8;
    }

    auto LOADT = [&](int t, short8* aa, short8* bb) {
        #pragma unroll
        for (int i = 0; i < 4; ++i) {
            aa[i] = *(const short8*)(Ab[i] + (size_t)t * 512);
            bb[i] = *(const short8*)(Bb[i] + (size_t)t * 512);
        }
    };
    auto MF = [&](short8* aa, short8* bb) {
        #pragma unroll
        for (int mi = 0; mi < 4; ++mi)
            #pragma unroll
            for (int ni = 0; ni < 4; ++ni)
                acc[mi][ni] = __builtin_amdgcn_mfma_f32_16x16x32_bf16(aa[mi], bb[ni], acc[mi][ni], 0, 0, 0);
    };

    short8 A0[4], B0[4], A1[4], B1[4];
    LOADT(0, A0, B0);
    for (int t = 0; t < nk; t += 2) {              // nk % 2 == 0
        LOADT(t + 1, A1, B1);
        MF(A0, B0);
        if (t + 2 < nk) LOADT(t + 2, A0, B0);
        MF(A1, B1);
    }

    float* Cf = (float*)Cv + (MODE == 0 ? (size_t)bz * SP * EMBED : 0);
    unsigned short* Cb = (unsigned short*)Cv;
    const int ln15 = lane & 15, kq = lane >> 4;
    const int nktN = N >> 5;
    const bool addb = (bz == 0);
    #pragma unroll
    for (int mi = 0; mi < 4; ++mi) {
        #pragma unroll
        for (int ni = 0; ni < 4; ++ni) {
            const int col = col0 + ni * 16 + ln15;
            const float bb = addb ? bias[col] : 0.0f;
            #pragma unroll
            for (int j = 0; j < 4; ++j) {
                const int row = row0 + mi * 16 + kq * 4 + j;
                if (row < M) {
                    float v = acc[mi][ni][j] + bb;
                    if (ACT == 1) v = fast_gelu(v);
                    if (MODE == 0)      Cf[(size_t)row * N + col] = v;
                    else if (MODE == 2) Cb[(size_t)row * N + col] = f2bf(v);
                    else                Cb[pidx(row, col, nktN)] = f2bf(v);
                }
            }
        }
    }
}

// ---------------- dilated attention: MFMA (bf16 qkv in, bf16 Obr out) ----------------
__global__ __launch_bounds__(256, 1)
void attn_kernel(const unsigned short* __restrict__ qkv,
                 unsigned short* __restrict__ Obr, float* __restrict__ Lbr) {
    const int bx = blockIdx.x, hh = blockIdx.y;
    int b, n;
    if      (bx < 17) { b = 0; n = bx; }
    else if (bx < 26) { b = 1; n = bx - 17; }
    else if (bx < 31) { b = 2; n = bx - 26; }
    else if (bx < 34) { b = 3; n = bx - 31; }
    else              { b = 4; n = bx - 34; }
    const int r = 1 << b;
    const int segw = 128 << b;
    const int base = n * segw + (hh & (r - 1));

    __shared__ __attribute__((aligned(16))) unsigned short VT[64 * 128];   // [d][k] swizzled
    __shared__ __attribute__((aligned(16))) unsigned short Pl[128 * 128];  // [q][k] swizzled

    const int tid = threadIdx.x;

    // ---- stage V^T (transposed + swizzled) ----
    {
        const int key = tid >> 1, dh2 = (tid & 1) * 32;
        const int pos = base + r * key;
        const bool val = pos < N_REAL;
        const unsigned short* vsrc = qkv + (size_t)(val ? pos : 0) * 2304 + 1536 + hh * 64 + dh2;
        #pragma unroll
        for (int u = 0; u < 4; ++u) {
            short8 vv = ((const short8*)vsrc)[u];
            #pragma unroll
            for (int e = 0; e < 8; ++e) {
                const int d = dh2 + u * 8 + e;
                VT[(d * 256 + ((key * 2) ^ ((d & 7) << 4))) >> 1] =
                    val ? (unsigned short)vv[e] : (unsigned short)0;
            }
        }
    }
    __syncthreads();

    const int lane = tid & 63, wv = tid >> 6;
    const int ln15 = lane & 15, kq = lane >> 4;

    // ---- QK^T ----
    f32x4 sc[2][8];
    #pragma unroll
    for (int mi = 0; mi < 2; ++mi)
        #pragma unroll
        for (int ni = 0; ni < 8; ++ni)
            #pragma unroll
            for (int j = 0; j < 4; ++j) sc[mi][ni][j] = 0.0f;

    #pragma unroll
    for (int kt = 0; kt < 2; ++kt) {
        short8 qfr[2], kfr[8];
        #pragma unroll
        for (int mi = 0; mi < 2; ++mi) {
            const int pos = base + r * (wv * 32 + mi * 16 + ln15);
            qfr[mi] = *(const short8*)(qkv + (size_t)(pos < N_REAL ? pos : 0) * 2304
                                       + hh * 64 + kt * 32 + kq * 8);
        }
        #pragma unroll
        for (int ni = 0; ni < 8; ++ni) {
            const int pos = base + r * (ni * 16 + ln15);
            kfr[ni] = *(const short8*)(qkv + (size_t)(pos < N_REAL ? pos : 0) * 2304
                                       + 768 + hh * 64 + kt * 32 + kq * 8);
        }
        #pragma unroll
        for (int mi = 0; mi < 2; ++mi)
            #pragma unroll
            for (int ni = 0; ni < 8; ++ni)
                sc[mi][ni] = __builtin_amdgcn_mfma_f32_16x16x32_bf16(qfr[mi], kfr[ni], sc[mi][ni], 0, 0, 0);
    }

    // scale + key mask
    #pragma unroll
    for (int ni = 0; ni < 8; ++ni) {
        const bool kval = (base + r * (ni * 16 + ln15)) < N_REAL;
        #pragma unroll
        for (int mi = 0; mi < 2; ++mi)
            #pragma unroll
            for (int j = 0; j < 4; ++j)
                sc[mi][ni][j] = kval ? sc[mi][ni][j] * 0.125f : NEGV;
    }

    // ---- wave-local row softmax ----
    float rsum[2][4];
    #pragma unroll
    for (int mi = 0; mi < 2; ++mi) {
        #pragma unroll
        for (int j = 0; j < 4; ++j) {
            float mx = sc[mi][0][j];
            #pragma unroll
            for (int ni = 1; ni < 8; ++ni) mx = fmaxf(mx, sc[mi][ni][j]);
            mx = fmaxf(mx, __shfl_xor(mx, 1));
            mx = fmaxf(mx, __shfl_xor(mx, 2));
            mx = fmaxf(mx, __shfl_xor(mx, 4));
            mx = fmaxf(mx, __shfl_xor(mx, 8));
            float sm = 0.f;
            #pragma unroll
            for (int ni = 0; ni < 8; ++ni) {
                float e = __expf(sc[mi][ni][j] - mx);
                sc[mi][ni][j] = e;
                sm += e;
            }
            sm += __shfl_xor(sm, 1);
            sm += __shfl_xor(sm, 2);
            sm += __shfl_xor(sm, 4);
            sm += __shfl_xor(sm, 8);
            rsum[mi][j] = sm;
            const int prow = wv * 32 + mi * 16 + kq * 4 + j;
            const int qpos = base + r * prow;
            if (ln15 == 0 && qpos < N_REAL)
                Lbr[((size_t)b * SP + qpos) * HEADS + hh] = mx + logf(sm);
        }
    }

    // ---- write P to LDS (bf16, swizzled) ----
    #pragma unroll
    for (int mi = 0; mi < 2; ++mi)
        #pragma unroll
        for (int j = 0; j < 4; ++j) {
            const int prow = wv * 32 + mi * 16 + kq * 4 + j;
            #pragma unroll
            for (int ni = 0; ni < 8; ++ni) {
                const int col = ni * 16 + ln15;
                Pl[(prow * 256 + ((col * 2) ^ ((prow & 7) << 4))) >> 1] = f2bf(sc[mi][ni][j]);
            }
        }
    __syncthreads();

    // ---- PV: O[32 q][64 d] per wave, K=128 ----
    f32x4 ov[2][4];
    #pragma unroll
    for (int mi = 0; mi < 2; ++mi)
        #pragma unroll
        for (int ni = 0; ni < 4; ++ni)
            #pragma unroll
            for (int j = 0; j < 4; ++j) ov[mi][ni][j] = 0.0f;

    #pragma unroll
    for (int kt = 0; kt < 4; ++kt) {
        short8 pa[2], vb[4];
        #pragma unroll
        for (int mi = 0; mi < 2; ++mi) {
            const int row = wv * 32 + mi * 16 + ln15;
            pa[mi] = *(const short8*)((const char*)Pl + row * 256
                                      + ((kt * 64 + kq * 16) ^ ((row & 7) << 4)));
        }
        #pragma unroll
        for (int ni = 0; ni < 4; ++ni) {
            const int d = ni * 16 + ln15;
            vb[ni] = *(const short8*)((const char*)VT + d * 256
                                      + ((kt * 64 + kq * 16) ^ ((d & 7) << 4)));
        }
        #pragma unroll
        for (int mi = 0; mi < 2; ++mi)
            #pragma unroll
            for (int ni = 0; ni < 4; ++ni)
                ov[mi][ni] = __builtin_amdgcn_mfma_f32_16x16x32_bf16(pa[mi], vb[ni], ov[mi][ni], 0, 0, 0);
    }

    // ---- epilogue: normalize + store ----
    #pragma unroll
    for (int mi = 0; mi < 2; ++mi)
        #pragma unroll
        for (int j = 0; j < 4; ++j) {
            const int prow = wv * 32 + mi * 16 + kq * 4 + j;
            const int qpos = base + r * prow;
            if (qpos < N_REAL) {
                const float inv = 1.0f / rsum[mi][j];
                #pragma unroll
                for (int ni = 0; ni < 4; ++ni)
                    Obr[((size_t)b * N_REAL + qpos) * EMBED + hh * 64 + ni * 16 + ln15] =
                        f2bf(ov[mi][ni][j] * inv);
            }
        }
}

// ---------------- branch combine -> packed bf16 (A-layout, nkt=24) ----------------
__global__ void combine_kernel(const unsigned short* __restrict__ Obr, const float* __restrict__ Lbr,
                               unsigned short* __restrict__ out) {
    int gid = blockIdx.x * 256 + threadIdx.x;
    if (gid >= N_REAL * EMBED) return;
    int p = gid / EMBED, e = gid - p * EMBED;
    int h = e >> 6;
    float l[5];
    float mx = NEGV;
    #pragma unroll
    for (int b = 0; b < 5; ++b) {
        const int rm = (1 << b) - 1;
        l[b] = ((p & rm) == (h & rm)) ? Lbr[((size_t)b * SP + p) * HEADS + h] : NEGV;
        mx = fmaxf(mx, l[b]);
    }
    float wsum = 0.f, acc = 0.f;
    #pragma unroll
    for (int b = 0; b < 5; ++b) {
        if (l[b] > NEGV * 0.5f) {
            float wt = expf(l[b] - mx);
            wsum += wt;
            acc += wt * bf2f(Obr[((size_t)b * N_REAL + p) * EMBED + e]);
        }
    }
    out[pidx(p, e, 24)] = f2bf(acc / wsum);
}

// ---------------- host orchestration ----------------
extern "C" void kernel_launch(void* const* d_in, const int* in_sizes, int n_in,
                              void* d_out, int out_size, void* d_ws, size_t ws_size,
                              hipStream_t stream) {
    const float* x      = (const float*)d_in[0];
    const float* conv_w = (const float*)d_in[1];
    const float* conv_b = (const float*)d_in[2];
    const float* cls    = (const float*)d_in[3];
    const float* pos    = (const float*)d_in[4];
    const float* ln1w   = (const float*)d_in[5];
    const float* ln1b   = (const float*)d_in[6];
    const float* wq     = (const float*)d_in[7];
    const float* bq     = (const float*)d_in[8];
    const float* wk     = (const float*)d_in[9];
    const float* bk     = (const float*)d_in[10];
    const float* wv     = (const float*)d_in[11];
    const float* bv     = (const float*)d_in[12];
    const float* wo     = (const float*)d_in[13];
    const float* bo     = (const float*)d_in[14];
    const float* ln2w   = (const float*)d_in[15];
    const float* ln2b   = (const float*)d_in[16];
    const float* w1     = (const float*)d_in[17];
    const float* b1     = (const float*)d_in[18];
    const float* w2     = (const float*)d_in[19];
    const float* b2     = (const float*)d_in[20];
    const float* lnfw   = (const float*)d_in[21];
    const float* lnfb   = (const float*)d_in[22];

    const size_t EE = (size_t)EMBED * EMBED;
    const size_t EM = (size_t)EMBED * MLP_DIM;

    // decide upfront vs per-layer weight packing based on ws_size (host-side, deterministic)
    const size_t base_floats =
        (size_t)SP * EMBED + 4 * (size_t)SP * EMBED + 5 * (size_t)SP * HEADS
        + (size_t)DEPTH * 2304 + (size_t)SPAD * 2304 / 2 + (size_t)SPAD * EMBED / 2
        + (size_t)SPAD * EMBED / 2 + (size_t)SPAD * MLP_DIM / 2 + (size_t)2112 * 1024 / 2
        + (size_t)EMBED * 1024 / 2 + ((size_t)5 * N_REAL * EMBED / 2 + 64);
    const size_t per_layer_floats = (3 * EE + EE + EM + EM) / 2;
    const bool up = ws_size >= (base_floats + 6 * per_layer_floats) * 4 + (1 << 20);
    const int NL = up ? DEPTH : 1;

    float* ws = (float*)d_ws;
    float* h     = ws;  ws += (size_t)SP * EMBED;
    float* tmp   = ws;  ws += (size_t)4 * SP * EMBED;
    float* Lbr   = ws;  ws += (size_t)5 * SP * HEADS;
    float* bqkv  = ws;  ws += (size_t)DEPTH * 2304;
    unsigned short* qkv_bf   = (unsigned short*)ws;  ws += (size_t)SPAD * 2304 / 2;
    unsigned short* xln_pk   = (unsigned short*)ws;  ws += (size_t)SPAD * EMBED / 2;
    unsigned short* attn_pk  = (unsigned short*)ws;  ws += (size_t)SPAD * EMBED / 2;
    unsigned short* mid_pk   = (unsigned short*)ws;  ws += (size_t)SPAD * MLP_DIM / 2;
    unsigned short* patch_pk = (unsigned short*)ws;  ws += (size_t)2112 * 1024 / 2;
    unsigned short* convw_pk = (unsigned short*)ws;  ws += (size_t)EMBED * 1024 / 2;
    unsigned short* Obr      = (unsigned short*)ws;  ws += (size_t)5 * N_REAL * EMBED / 2 + 64;
    unsigned short* wqkv_pk  = (unsigned short*)ws;  ws += (size_t)NL * 3 * EE / 2;
    unsigned short* wo_pk    = (unsigned short*)ws;  ws += (size_t)NL * EE / 2;
    unsigned short* w1_pk    = (unsigned short*)ws;  ws += (size_t)NL * EM / 2;
    unsigned short* w2_pk    = (unsigned short*)ws;  ws += (size_t)NL * EM / 2;

    // ---- upfront packing / init ----
    if (up) {
        prep_mega_kernel<<<6 * 1728 + 192 + 2048 + 57, 256, 0, stream>>>(
            x, conv_w, wq, wk, wv, wo, w1, w2, bq, bk, bv, cls, pos,
            patch_pk, convw_pk, bqkv, h, wqkv_pk, wo_pk, w1_pk, w2_pk);
    } else {
        im2col_kernel<<<2048, 256, 0, stream>>>(x, patch_pk);
        pack_NK_kernel<<<dim3(6, 32), 256, 0, stream>>>(conv_w, convw_pk, EMBED, 1024);
        init_misc_kernel<<<(DEPTH * 2304 + EMBED + 255) / 256, 256, 0, stream>>>(
            bq, bk, bv, bqkv, cls, pos, h);
    }
    // patch GEMM -> 4 f32 partials, then merge with pos
    gemm_bf16<0, 0><<<384, 256, 0, stream>>>(patch_pk, convw_pk, conv_b,
                                             tmp, 2048, EMBED, 1024, 6, 16, 4);
    embed_add_kernel<<<(2048 * EMBED + 255) / 256, 256, 0, stream>>>(pos, tmp, h);

    for (int L = 0; L < DEPTH; ++L) {
        const int off = up ? L : 0;
        unsigned short* qkvW = wqkv_pk + (size_t)off * 3 * EE;
        unsigned short* woW  = wo_pk   + (size_t)off * EE;
        unsigned short* w1W  = w1_pk   + (size_t)off * EM;
        unsigned short* w2W  = w2_pk   + (size_t)off * EM;
        if (!up)
            pack_all_kernel<<<1728, 256, 0, stream>>>(wq + L * EE, wk + L * EE, wv + L * EE,
                                                      wo + L * EE, w1 + L * EM, w2 + L * EM,
                                                      qkvW, woW, w1W, w2W);

        // LN1 -> packed bf16 (layer 0: h final; layers 1..5: fold prev MLP2's 4 partials)
        if (L == 0)
            ln_kernel<true><<<N_REAL, 256, 0, stream>>>(h, xln_pk, ln1w + (size_t)L * EMBED,
                                                        ln1b + (size_t)L * EMBED, N_REAL);
        else
            ln_res_kernel<true><<<N_REAL, 256, 0, stream>>>(h, tmp, 4, xln_pk,
                                                            ln1w + (size_t)L * EMBED,
                                                            ln1b + (size_t)L * EMBED, N_REAL);
        // fused QKV -> row-major bf16
        gemm_bf16<0, 2><<<306, 256, 0, stream>>>(xln_pk, qkvW, bqkv + (size_t)L * 2304,
                                                 qkv_bf, N_REAL, 2304, EMBED, 18, 17, 1);
        // dilated attention (MFMA)
        attn_kernel<<<dim3(36, 12), 256, 0, stream>>>(qkv_bf, Obr, Lbr);
        combine_kernel<<<((N_REAL * EMBED) + 255) / 256, 256, 0, stream>>>(Obr, Lbr, attn_pk);
        // O-projection -> 4 f32 partials
        gemm_bf16<0, 0><<<408, 256, 0, stream>>>(attn_pk, woW, bo + (size_t)L * EMBED,
                                                 tmp, N_REAL, EMBED, EMBED, 6, 17, 4);
        // LN2 folds O-proj partials into h -> packed bf16
        ln_res_kernel<true><<<N_REAL, 256, 0, stream>>>(h, tmp, 4, xln_pk,
                                                        ln2w + (size_t)L * EMBED,
                                                        ln2b + (size_t)L * EMBED, N_REAL);
        gemm_bf16<1, 3><<<408, 256, 0, stream>>>(xln_pk, w1W, b1 + (size_t)L * MLP_DIM,
                                                 mid_pk, N_REAL, MLP_DIM, EMBED, 24, 17, 1);
        // MLP2 -> 4 f32 partials (folded by next LN1 / final LN)
        gemm_bf16<0, 0><<<408, 256, 0, stream>>>(mid_pk, w2W, b2 + (size_t)L * EMBED,
                                                 tmp, N_REAL, EMBED, MLP_DIM, 6, 17, 4);
    }

    // final LN on row 0 (folds last MLP2 partials) -> d_out (768 fp32)
    ln_res_kernel<false><<<1, 256, 0, stream>>>(h, tmp, 4, (float*)d_out, lnfw, lnfb, 1);
}